// Round 6
// baseline (4239.351 us; speedup 1.0000x reference)
//
#include <hip/hip_runtime.h>
#include <math.h>

// Problem constants
#define B_    128
#define P_    197
#define D_    768
#define TOK_  512
#define K_    16
#define TOPK_ 8
#define L_    2
#define H_    12
#define HD_   64
#define NTOK  213            // K_ + P_
#define MROWS (B_ * NTOK)    // 27264

typedef _Float16 f16;
typedef __attribute__((ext_vector_type(8))) _Float16 f16x8;
typedef __attribute__((ext_vector_type(4))) _Float16 f16x4;
typedef __attribute__((ext_vector_type(4))) float f32x4;

__device__ __forceinline__ void gload_lds16(const void* g, void* l) {
  __builtin_amdgcn_global_load_lds(
      (const __attribute__((address_space(1))) unsigned int*)g,
      (__attribute__((address_space(3))) unsigned int*)l, 16, 0, 0);
}

__device__ __forceinline__ float wred_sum(float v) {
#pragma unroll
  for (int o = 32; o > 0; o >>= 1) v += __shfl_xor(v, o);
  return v;
}
__device__ __forceinline__ float wred_max(float v) {
#pragma unroll
  for (int o = 32; o > 0; o >>= 1) v = fmaxf(v, __shfl_xor(v, o));
  return v;
}

// ---------------- concat: x = [templates broadcast | img_patch_feats] ----
__global__ __launch_bounds__(256) void concat_kernel(
    const float* __restrict__ tpl, const float* __restrict__ patches,
    float* __restrict__ x) {
  size_t i = (size_t)blockIdx.x * 256 + threadIdx.x;  // one float4 each
  const size_t total = (size_t)MROWS * (D_ / 4);
  if (i >= total) return;
  size_t row = i / (D_ / 4);
  int c = (int)(i % (D_ / 4)) * 4;
  size_t b = row / NTOK;
  int n = (int)(row % NTOK);
  float4 v;
  if (n < K_) v = *(const float4*)(tpl + (size_t)n * D_ + c);
  else        v = *(const float4*)(patches + ((size_t)b * P_ + (n - K_)) * D_ + c);
  *(float4*)(x + row * D_ + c) = v;
}

// ---------------- LayerNorm: one wave per row, f16 hi/lo split out --------
__global__ __launch_bounds__(64) void ln_split_kernel(
    const float* __restrict__ x, const float* __restrict__ w,
    const float* __restrict__ b, f16* __restrict__ yh, f16* __restrict__ yl) {
  size_t row = blockIdx.x;
  int lane = threadIdx.x;
  const float* xr = x + row * D_;
  float4 v[3];
#pragma unroll
  for (int j = 0; j < 3; ++j) v[j] = *(const float4*)(xr + j * 256 + lane * 4);
  float s = 0.f, sq = 0.f;
#pragma unroll
  for (int j = 0; j < 3; ++j) {
    s += v[j].x + v[j].y + v[j].z + v[j].w;
    sq = fmaf(v[j].x, v[j].x, sq); sq = fmaf(v[j].y, v[j].y, sq);
    sq = fmaf(v[j].z, v[j].z, sq); sq = fmaf(v[j].w, v[j].w, sq);
  }
#pragma unroll
  for (int o = 32; o > 0; o >>= 1) { s += __shfl_xor(s, o); sq += __shfl_xor(sq, o); }
  float mean = s * (1.f / D_);
  float var = sq * (1.f / D_) - mean * mean;
  float rs = rsqrtf(var + 1e-5f);
#pragma unroll
  for (int j = 0; j < 3; ++j) {
    int col = j * 256 + lane * 4;
    float4 wv = *(const float4*)(w + col);
    float4 bv = *(const float4*)(b + col);
    float o0 = (v[j].x - mean) * rs * wv.x + bv.x;
    float o1 = (v[j].y - mean) * rs * wv.y + bv.y;
    float o2 = (v[j].z - mean) * rs * wv.z + bv.z;
    float o3 = (v[j].w - mean) * rs * wv.w + bv.w;
    f16x4 hi = {(f16)o0, (f16)o1, (f16)o2, (f16)o3};
    f16x4 lo = {(f16)(o0 - (float)hi[0]), (f16)(o1 - (float)hi[1]),
                (f16)(o2 - (float)hi[2]), (f16)(o3 - (float)hi[3])};
    *(f16x4*)&yh[row * D_ + col] = hi;
    *(f16x4*)&yl[row * D_ + col] = lo;
  }
}

// -------- weight transpose + f16 hi/lo split: W[K][N] -> Wt[N][K] --------
__global__ __launch_bounds__(256) void transpose_split(
    const float* __restrict__ W, f16* __restrict__ Wh, f16* __restrict__ Wl,
    int Kd, int Nd) {
  __shared__ float t[32][33];
  const int n0 = blockIdx.x * 32, k0 = blockIdx.y * 32;
  const int tx = threadIdx.x & 31, ty = threadIdx.x >> 5;  // 32 x 8
#pragma unroll
  for (int j = 0; j < 4; ++j)
    t[ty + 8 * j][tx] = W[(size_t)(k0 + ty + 8 * j) * Nd + n0 + tx];
  __syncthreads();
#pragma unroll
  for (int j = 0; j < 4; ++j) {
    float v = t[tx][ty + 8 * j];
    f16 hi = (f16)v;
    size_t off = (size_t)(n0 + ty + 8 * j) * Kd + k0 + tx;
    Wh[off] = hi;
    Wl[off] = (f16)(v - (float)hi);
  }
}

// ------- split-f16 MFMA GEMM: C = act(A @ Wt^T + bias) [+C] --------------
// A = Ah+Al (hi/lo f16 planes, [M][K]); Wt = Wh+Wl ([N][K]).
// acc += Ah*Wh + Ah*Wl + Al*Wh  (error ~2^-21 — near-fp32).
// BM=BN=128, BK=32, 256 thr = 4 waves (2x2), wave = 64x64 via 4x4 frags.
// Staging via global_load_lds(16B) into linear [128][32] LDS with chunk
// swizzle c_p = c_l ^ ((row>>1)&3): gload writes linearly (source address
// inverse-permuted per lane), ds_read_b128 lands 2-way per 16-lane phase.
// ACT: 0 none, 1 relu, 2 sigmoid. OUTSPLIT: write f16 hi/lo planes.
template <int ACT, bool RESID, bool OUTSPLIT>
__global__ __launch_bounds__(256) void gemm_split(
    const f16* __restrict__ Ah, const f16* __restrict__ Al,
    const f16* __restrict__ Wh, const f16* __restrict__ Wl,
    const float* __restrict__ bias, float* __restrict__ Cf,
    f16* __restrict__ Ch, f16* __restrict__ Cl, int M, int N, int K) {
  __shared__ __align__(16) f16 Ash[128][32];
  __shared__ __align__(16) f16 Asl[128][32];
  __shared__ __align__(16) f16 Bsh[128][32];
  __shared__ __align__(16) f16 Bsl[128][32];
  const int tid = threadIdx.x;
  const int bm = blockIdx.x * 128, bn = blockIdx.y * 128;
  const int w = tid >> 6, lane = tid & 63;
  const int wm = (w & 1) * 64, wn = (w >> 1) * 64;
  const int fr = lane & 15, kg = lane >> 4;
  f32x4 acc[4][4];
  const f32x4 z = {0.f, 0.f, 0.f, 0.f};
#pragma unroll
  for (int i = 0; i < 4; ++i)
#pragma unroll
    for (int j = 0; j < 4; ++j) acc[i][j] = z;
  // staging geometry: thread fetches the chunk destined for its linear slot
  const int srow = tid >> 2;                          // dest row (+64 for j=1)
  const int c_l  = (tid & 3) ^ ((tid >> 3) & 3);      // logical k-chunk to fetch
  const int cswz = (kg ^ ((fr >> 1) & 3)) * 8;        // physical chunk on read
  for (int k0 = 0; k0 < K; k0 += 32) {
#pragma unroll
    for (int j = 0; j < 2; ++j) {
      int arow = bm + j * 64 + srow; if (arow >= M) arow = M - 1;  // stores guarded
      int brow = bn + j * 64 + srow;
      size_t aoff = (size_t)arow * K + k0 + c_l * 8;
      size_t boff = (size_t)brow * K + k0 + c_l * 8;
      char* dA = (char*)&Ash[0][0] + j * 4096 + w * 1024;
      char* dB = (char*)&Bsh[0][0] + j * 4096 + w * 1024;
      char* dAl = (char*)&Asl[0][0] + j * 4096 + w * 1024;
      char* dBl = (char*)&Bsl[0][0] + j * 4096 + w * 1024;
      gload_lds16(Ah + aoff, dA);
      gload_lds16(Al + aoff, dAl);
      gload_lds16(Wh + boff, dB);
      gload_lds16(Wl + boff, dBl);
    }
    __syncthreads();
    f16x8 ah[4], al[4], bh[4], bl[4];
#pragma unroll
    for (int i = 0; i < 4; ++i) {
      ah[i] = *(const f16x8*)&Ash[wm + i * 16 + fr][cswz];
      al[i] = *(const f16x8*)&Asl[wm + i * 16 + fr][cswz];
      bh[i] = *(const f16x8*)&Bsh[wn + i * 16 + fr][cswz];
      bl[i] = *(const f16x8*)&Bsl[wn + i * 16 + fr][cswz];
    }
#pragma unroll
    for (int i = 0; i < 4; ++i)
#pragma unroll
      for (int j = 0; j < 4; ++j) {
        acc[i][j] = __builtin_amdgcn_mfma_f32_16x16x32_f16(ah[i], bh[j], acc[i][j], 0, 0, 0);
        acc[i][j] = __builtin_amdgcn_mfma_f32_16x16x32_f16(ah[i], bl[j], acc[i][j], 0, 0, 0);
        acc[i][j] = __builtin_amdgcn_mfma_f32_16x16x32_f16(al[i], bh[j], acc[i][j], 0, 0, 0);
      }
    __syncthreads();
  }
  // epilogue: D[row=(lane>>4)*4+rg][col=lane&15] per fragment (m89 layout)
#pragma unroll
  for (int j = 0; j < 4; ++j) {
    const int gc = bn + wn + j * 16 + fr;
    const float bv = bias[gc];
#pragma unroll
    for (int i = 0; i < 4; ++i) {
#pragma unroll
      for (int rg = 0; rg < 4; ++rg) {
        int gr = bm + wm + i * 16 + kg * 4 + rg;
        if (gr < M) {
          float val = acc[i][j][rg] + bv;
          if (ACT == 1) val = fmaxf(val, 0.f);
          if (ACT == 2) val = 1.f / (1.f + expf(-val));
          size_t off = (size_t)gr * N + gc;
          if (OUTSPLIT) {
            f16 hi = (f16)val;
            Ch[off] = hi;
            Cl[off] = (f16)(val - (float)hi);
          } else {
            if (RESID) val += Cf[off];
            Cf[off] = val;
          }
        }
      }
    }
  }
}

// ---------------- flash attention, fp32 in/compute, f16-split out ---------
// Grid (NB, H, 7): 32 q-rows/block, 4 waves x 8 rows. K-tile + transposed
// V-tile in XOR-swizzled [64][64] fp32 LDS. Online softmax.
__global__ __launch_bounds__(256) void attn_kernel2(
    const float* __restrict__ q, const float* __restrict__ kv,
    f16* __restrict__ oh, f16* __restrict__ ol) {
  __shared__ __align__(16) float Kt[64][64];   // Kt[tok][(d4^(tok&15))*4+i]
  __shared__ __align__(16) float Vt[64][64];   // Vt[d][(tg^(d&15))*4+ti]
  __shared__ __align__(16) float qs[4][8][64];
  __shared__ __align__(16) float ps[4][8][64];
  const int b = blockIdx.x, h = blockIdx.y, qt = blockIdx.z;
  const int tid = threadIdx.x, w = tid >> 6, lane = tid & 63;
  const int n0 = qt * 32;
  float o_r[8], m_r[8], l_r[8];
#pragma unroll
  for (int r = 0; r < 8; ++r) { o_r[r] = 0.f; m_r[r] = -INFINITY; l_r[r] = 0.f; }
#pragma unroll
  for (int r = 0; r < 8; ++r) {
    int n = n0 + w * 8 + r;
    if (n >= NTOK) n = NTOK - 1;       // clamp; stores guarded
    qs[w][r][lane] = q[((size_t)(b * NTOK + n)) * D_ + h * HD_ + lane];
  }
  const int swz = lane & 15;
  const f32x4 z4 = {0.f, 0.f, 0.f, 0.f};
  for (int t = 0; t < 4; ++t) {
    const int t0 = t * 64;
    const int TT = (NTOK - t0) < 64 ? (NTOK - t0) : 64;
    __syncthreads();                   // prior tile fully consumed
    for (int s = tid; s < 1024; s += 256) {
      int tok = s >> 4, d4 = s & 15;
      int tkc = tok < TT ? tok : TT - 1;
      size_t base = ((size_t)(b * NTOK + t0 + tkc) * 2) * D_ + h * HD_ + d4 * 4;
      f32x4 kvec = *(const f32x4*)&kv[base];
      *(f32x4*)&Kt[tok][(d4 ^ (tok & 15)) * 4] = kvec;
      f32x4 vvec = *(const f32x4*)&kv[base + D_];
      int tg = tok >> 2, ti = tok & 3;
#pragma unroll
      for (int i = 0; i < 4; ++i) {
        int dd = d4 * 4 + i;
        Vt[dd][((tg ^ (dd & 15)) << 2) | ti] = vvec[i];
      }
    }
    __syncthreads();
    // ---- scores: lane = token ----
    f32x4 sacc[8];
#pragma unroll
    for (int r = 0; r < 8; ++r) sacc[r] = z4;
#pragma unroll 4
    for (int d4 = 0; d4 < 16; ++d4) {
      f32x4 kvv = *(const f32x4*)&Kt[lane][(d4 ^ swz) * 4];
#pragma unroll
      for (int r = 0; r < 8; ++r) {
        f32x4 qv = *(const f32x4*)&qs[w][r][d4 * 4];
        sacc[r] += kvv * qv;
      }
    }
#pragma unroll
    for (int r = 0; r < 8; ++r) {
      float sv = (sacc[r][0] + sacc[r][1]) + (sacc[r][2] + sacc[r][3]);
      sv *= 0.125f;                    // hd^-0.5
      if (lane >= TT) sv = -INFINITY;
      float tmax = wred_max(sv);
      float newm = fmaxf(m_r[r], tmax);
      float e = __expf(sv - newm);     // -inf -> 0
      float tsum = wred_sum(e);
      float scale = __expf(m_r[r] - newm);
      m_r[r] = newm;
      l_r[r] = l_r[r] * scale + tsum;
      o_r[r] *= scale;
      ps[w][r][lane] = e;
    }
    // ---- PV: lane = d ----
    f32x4 pacc[8];
#pragma unroll
    for (int r = 0; r < 8; ++r) pacc[r] = z4;
    const int nm4 = (TT + 3) >> 2;
#pragma unroll 4
    for (int m4 = 0; m4 < nm4; ++m4) {
      f32x4 vv = *(const f32x4*)&Vt[lane][(m4 ^ swz) * 4];
#pragma unroll
      for (int r = 0; r < 8; ++r) {
        f32x4 pv = *(const f32x4*)&ps[w][r][m4 * 4];
        pacc[r] += vv * pv;
      }
    }
#pragma unroll
    for (int r = 0; r < 8; ++r)
      o_r[r] += (pacc[r][0] + pacc[r][1]) + (pacc[r][2] + pacc[r][3]);
  }
#pragma unroll
  for (int r = 0; r < 8; ++r) {
    int n = n0 + w * 8 + r;
    if (n < NTOK) {
      float val = o_r[r] / l_r[r];
      size_t off = ((size_t)(b * NTOK + n)) * D_ + h * HD_ + lane;
      f16 hi = (f16)val;
      oh[off] = hi;
      ol[off] = (f16)(val - (float)hi);
    }
  }
}

// ---------- gather x[:, :16, :] -> f16 hi/lo planes [2048][768] -----------
__global__ __launch_bounds__(256) void gather_split(
    const float* __restrict__ x, f16* __restrict__ oh, f16* __restrict__ ol) {
  int idx = blockIdx.x * 256 + threadIdx.x;
  if (idx >= B_ * K_ * (D_ / 4)) return;
  int row = idx / (D_ / 4);
  int c4 = (idx % (D_ / 4)) * 4;
  int b = row >> 4, k = row & 15;
  const float* src = x + ((size_t)(b * NTOK + k)) * D_ + c4;
  f16x4 hi, lo;
#pragma unroll
  for (int i = 0; i < 4; ++i) {
    float v = src[i];
    hi[i] = (f16)v;
    lo[i] = (f16)(v - (float)hi[i]);
  }
  *(f16x4*)&oh[(size_t)row * D_ + c4] = hi;
  *(f16x4*)&ol[(size_t)row * D_ + c4] = lo;
}

// ---------------- logits[b,k] = dot(lat[b,k,:], proj[b,:]) ----------------
__global__ __launch_bounds__(64) void logits_kernel(
    const float* __restrict__ lat, const float* __restrict__ proj,
    float* __restrict__ logits) {
  int bk = blockIdx.x;
  int b = bk >> 4;
  int lane = threadIdx.x;
  const float* lr = lat + (size_t)bk * TOK_;
  const float* pr = proj + (size_t)b * TOK_;
  float s = 0.f;
#pragma unroll
  for (int i = 0; i < 8; ++i) s = fmaf(lr[lane + 64 * i], pr[lane + 64 * i], s);
  s = wred_sum(s);
  if (lane == 0) logits[bk] = s;
}

// ---------------- softmax + topk select + normalize (1 wave per b) --------
__global__ __launch_bounds__(64) void select_kernel(
    const float* __restrict__ logits, const float* __restrict__ lat,
    float* __restrict__ out_sel, float* __restrict__ out_numr) {
  const int b = blockIdx.x;
  const int lane = threadIdx.x;
  __shared__ float aw_s[16];
  __shared__ int sel_id_s[8];
  __shared__ int numr_s;
  float v = (lane < 16) ? logits[b * 16 + lane] : -INFINITY;
  float mx = wred_max(v);
  float e = (lane < 16) ? expf(v - mx) : 0.f;
  float sum = wred_sum(e);
  float aw = e / sum;
  if (lane < 16) aw_s[lane] = aw;
  unsigned long long ball = __ballot(lane < 16 && aw > 0.05f);
  int counts = __popcll(ball);
  __syncthreads();
  if (lane == 0) {
    int num_r = counts < 1 ? 1 : (counts > TOPK_ ? TOPK_ : counts);
    numr_s = num_r;
    bool used[16];
#pragma unroll
    for (int i = 0; i < 16; ++i) used[i] = false;
    int sorted_idx[8];
    for (int j = 0; j < 8; ++j) {   // descending top-8 (ties: lowest index)
      float bv = -INFINITY; int bi = 0;
      for (int i = 0; i < 16; ++i)
        if (!used[i] && aw_s[i] > bv) { bv = aw_s[i]; bi = i; }
      used[bi] = true;
      sorted_idx[j] = bi;
    }
    int keys[8];
    for (int j = 0; j < 8; ++j) keys[j] = (j < num_r) ? sorted_idx[j] : (16 + j);
    bool kused[8];
    for (int j = 0; j < 8; ++j) kused[j] = false;
    for (int slot = 0; slot < 8; ++slot) {  // perm = argsort(keys), gather
      int bk = 1 << 30, bj = 0;
      for (int j = 0; j < 8; ++j)
        if (!kused[j] && keys[j] < bk) { bk = keys[j]; bj = j; }
      kused[bj] = true;
      sel_id_s[slot] = sorted_idx[bj];
    }
  }
  __syncthreads();
  for (int j = 0; j < 8; ++j) {
    int id = sel_id_s[j];
    const float* row = lat + ((size_t)b * 16 + id) * TOK_;
    float vals[8];
    float sq = 0.f;
#pragma unroll
    for (int i = 0; i < 8; ++i) {
      vals[i] = row[lane + 64 * i];
      sq = fmaf(vals[i], vals[i], sq);
    }
    sq = wred_sum(sq);
    float inv = 1.f / fmaxf(sqrtf(sq), 1e-12f);
#pragma unroll
    for (int i = 0; i < 8; ++i)
      out_sel[((size_t)b * 8 + j) * TOK_ + lane + 64 * i] = vals[i] * inv;
  }
  if (lane == 0) out_numr[b] = (float)numr_s;
}

// ---------------- host launcher -------------------------------------------
extern "C" void kernel_launch(void* const* d_in, const int* in_sizes, int n_in,
                              void* d_out, int out_size, void* d_ws, size_t ws_size,
                              hipStream_t stream) {
  const float* img_feature_proj = (const float*)d_in[0];
  const float* img_patch_feats  = (const float*)d_in[1];
  const float* templates        = (const float*)d_in[2];
  const float* ln1_w  = (const float*)d_in[3];
  const float* ln1_b  = (const float*)d_in[4];
  const float* q_w    = (const float*)d_in[5];
  const float* q_b    = (const float*)d_in[6];
  const float* kv_w   = (const float*)d_in[7];
  const float* kv_b   = (const float*)d_in[8];
  const float* proj_w = (const float*)d_in[9];
  const float* proj_b = (const float*)d_in[10];
  const float* ln2_w  = (const float*)d_in[11];
  const float* ln2_b  = (const float*)d_in[12];
  const float* fc1_w  = (const float*)d_in[13];
  const float* fc1_b  = (const float*)d_in[14];
  const float* fc2_w  = (const float*)d_in[15];
  const float* fc2_b  = (const float*)d_in[16];
  const float* att_fc_w = (const float*)d_in[17];
  const float* att_fc_b = (const float*)d_in[18];

  // ---- fixed workspace (~115 MB) ----
  char* ws = (char*)d_ws;
  const size_t XB = (size_t)MROWS * D_ * 4;              // 83,755,008 B
  float* x_f = (float*)ws;  ws += XB;                    // residual fp32
  auto alloc_f16 = [&](size_t n) { f16* p = (f16*)ws; ws += n * 2; return p; };
  f16* wq_h  = alloc_f16((size_t)768 * 768);
  f16* wq_l  = alloc_f16((size_t)768 * 768);
  f16* wkv_h = alloc_f16((size_t)1536 * 768);
  f16* wkv_l = alloc_f16((size_t)1536 * 768);
  f16* wp_h  = alloc_f16((size_t)768 * 768);
  f16* wp_l  = alloc_f16((size_t)768 * 768);
  f16* wf1_h = alloc_f16((size_t)1536 * 768);
  f16* wf1_l = alloc_f16((size_t)1536 * 768);
  f16* wf2_h = alloc_f16((size_t)768 * 1536);
  f16* wf2_l = alloc_f16((size_t)768 * 1536);
  f16* awt_h = alloc_f16((size_t)512 * 768);
  f16* awt_l = alloc_f16((size_t)512 * 768);
  f16* lat_h = alloc_f16((size_t)2048 * 768);
  f16* lat_l = alloc_f16((size_t)2048 * 768);
  float* lat    = (float*)ws; ws += (size_t)2048 * 512 * 4;
  float* logits = (float*)ws; ws += 8192;
  const size_t fixed_bytes = (size_t)(ws - (char*)d_ws);

  // ---- adaptive batch-chunk: h planes(4B) + q_f(4B) + kv_f(8B) per elem
  int NB = B_;
  while (NB > 1) {
    size_t CHE = (size_t)NB * NTOK * D_;
    if (fixed_bytes + 16 * CHE <= ws_size) break;
    NB >>= 1;
  }
  const size_t CHE = (size_t)NB * NTOK * D_;
  f16* h_h = (f16*)ws;                         // CHE f16
  f16* h_l = h_h + CHE;                        // CHE f16
  float* q_f  = (float*)(h_l + CHE);           // CHE f32
  float* kv_f = q_f + CHE;                     // 2*CHE f32
  f16* fc1o_h = (f16*)q_f;                     // alias: 2*CHE f16
  f16* fc1o_l = (f16*)kv_f;                    // alias: 2*CHE f16

  // ---- concat ----
  {
    size_t total = (size_t)MROWS * (D_ / 4);
    concat_kernel<<<(unsigned)((total + 255) / 256), 256, 0, stream>>>(
        templates, img_patch_feats, x_f);
  }
  transpose_split<<<dim3(16, 24), 256, 0, stream>>>(att_fc_w, awt_h, awt_l, 768, 512);

  const int nchunks = B_ / NB;
  for (int l = 0; l < L_; ++l) {
    transpose_split<<<dim3(24, 24), 256, 0, stream>>>(q_w + (size_t)l * 768 * 768, wq_h, wq_l, 768, 768);
    transpose_split<<<dim3(48, 24), 256, 0, stream>>>(kv_w + (size_t)l * 768 * 1536, wkv_h, wkv_l, 768, 1536);
    transpose_split<<<dim3(24, 24), 256, 0, stream>>>(proj_w + (size_t)l * 768 * 768, wp_h, wp_l, 768, 768);
    transpose_split<<<dim3(48, 24), 256, 0, stream>>>(fc1_w + (size_t)l * 768 * 1536, wf1_h, wf1_l, 768, 1536);
    transpose_split<<<dim3(24, 48), 256, 0, stream>>>(fc2_w + (size_t)l * 1536 * 768, wf2_h, wf2_l, 1536, 768);
    for (int c = 0; c < nchunks; ++c) {
      const int b0 = c * NB;
      const int Rc = NB * NTOK;
      const int mt = (Rc + 127) / 128;
      float* xc = x_f + (size_t)b0 * NTOK * D_;
      ln_split_kernel<<<Rc, 64, 0, stream>>>(xc, ln1_w + l * D_, ln1_b + l * D_, h_h, h_l);
      gemm_split<0, false, false><<<dim3(mt, 6), 256, 0, stream>>>(
          h_h, h_l, wq_h, wq_l, q_b + l * D_, q_f, nullptr, nullptr, Rc, 768, 768);
      gemm_split<0, false, false><<<dim3(mt, 12), 256, 0, stream>>>(
          h_h, h_l, wkv_h, wkv_l, kv_b + l * 1536, kv_f, nullptr, nullptr, Rc, 1536, 768);
      attn_kernel2<<<dim3(NB, H_, 7), 256, 0, stream>>>(q_f, kv_f, h_h, h_l);
      gemm_split<0, true, false><<<dim3(mt, 6), 256, 0, stream>>>(
          h_h, h_l, wp_h, wp_l, proj_b + l * D_, xc, nullptr, nullptr, Rc, 768, 768);
      ln_split_kernel<<<Rc, 64, 0, stream>>>(xc, ln2_w + l * D_, ln2_b + l * D_, h_h, h_l);
      gemm_split<1, false, true><<<dim3(mt, 12), 256, 0, stream>>>(
          h_h, h_l, wf1_h, wf1_l, fc1_b + l * 1536, nullptr, fc1o_h, fc1o_l, Rc, 1536, 768);
      gemm_split<0, true, false><<<dim3(mt, 6), 256, 0, stream>>>(
          fc1o_h, fc1o_l, wf2_h, wf2_l, fc2_b + l * D_, xc, nullptr, nullptr, Rc, 768, 1536);
    }
  }

  gather_split<<<(B_ * K_ * (D_ / 4) + 255) / 256, 256, 0, stream>>>(x_f, lat_h, lat_l);
  gemm_split<2, false, false><<<dim3(16, 4), 256, 0, stream>>>(
      lat_h, lat_l, awt_h, awt_l, att_fc_b, lat, nullptr, nullptr, B_ * K_, TOK_, 768);

  logits_kernel<<<B_ * K_, 64, 0, stream>>>(lat, img_feature_proj, logits);
  select_kernel<<<B_, 64, 0, stream>>>(logits, lat, (float*)d_out,
                                       (float*)d_out + (size_t)B_ * TOPK_ * TOK_);
}

// Round 7
// 3938.720 us; speedup vs baseline: 1.0763x; 1.0763x over previous
//
#include <hip/hip_runtime.h>
#include <math.h>

// Problem constants
#define B_    128
#define P_    197
#define D_    768
#define TOK_  512
#define K_    16
#define TOPK_ 8
#define L_    2
#define H_    12
#define HD_   64
#define NTOK  213            // K_ + P_
#define MROWS (B_ * NTOK)    // 27264

typedef _Float16 f16;
typedef __attribute__((ext_vector_type(8))) _Float16 f16x8;
typedef __attribute__((ext_vector_type(4))) _Float16 f16x4;
typedef __attribute__((ext_vector_type(4))) float f32x4;

__device__ __forceinline__ void gload_lds16(const void* g, void* l) {
  __builtin_amdgcn_global_load_lds(
      (const __attribute__((address_space(1))) unsigned int*)g,
      (__attribute__((address_space(3))) unsigned int*)l, 16, 0, 0);
}

__device__ __forceinline__ float wred_sum(float v) {
#pragma unroll
  for (int o = 32; o > 0; o >>= 1) v += __shfl_xor(v, o);
  return v;
}
__device__ __forceinline__ float wred_max(float v) {
#pragma unroll
  for (int o = 32; o > 0; o >>= 1) v = fmaxf(v, __shfl_xor(v, o));
  return v;
}

// ---------------- concat: x = [templates broadcast | img_patch_feats] ----
__global__ __launch_bounds__(256) void concat_kernel(
    const float* __restrict__ tpl, const float* __restrict__ patches,
    float* __restrict__ x) {
  size_t i = (size_t)blockIdx.x * 256 + threadIdx.x;  // one float4 each
  const size_t total = (size_t)MROWS * (D_ / 4);
  if (i >= total) return;
  size_t row = i / (D_ / 4);
  int c = (int)(i % (D_ / 4)) * 4;
  size_t b = row / NTOK;
  int n = (int)(row % NTOK);
  float4 v;
  if (n < K_) v = *(const float4*)(tpl + (size_t)n * D_ + c);
  else        v = *(const float4*)(patches + ((size_t)b * P_ + (n - K_)) * D_ + c);
  *(float4*)(x + row * D_ + c) = v;
}

// ---------------- LayerNorm: one wave per row, f16 hi/lo split out --------
__global__ __launch_bounds__(64) void ln_split_kernel(
    const float* __restrict__ x, const float* __restrict__ w,
    const float* __restrict__ b, f16* __restrict__ yh, f16* __restrict__ yl) {
  size_t row = blockIdx.x;
  int lane = threadIdx.x;
  const float* xr = x + row * D_;
  float4 v[3];
#pragma unroll
  for (int j = 0; j < 3; ++j) v[j] = *(const float4*)(xr + j * 256 + lane * 4);
  float s = 0.f, sq = 0.f;
#pragma unroll
  for (int j = 0; j < 3; ++j) {
    s += v[j].x + v[j].y + v[j].z + v[j].w;
    sq = fmaf(v[j].x, v[j].x, sq); sq = fmaf(v[j].y, v[j].y, sq);
    sq = fmaf(v[j].z, v[j].z, sq); sq = fmaf(v[j].w, v[j].w, sq);
  }
#pragma unroll
  for (int o = 32; o > 0; o >>= 1) { s += __shfl_xor(s, o); sq += __shfl_xor(sq, o); }
  float mean = s * (1.f / D_);
  float var = sq * (1.f / D_) - mean * mean;
  float rs = rsqrtf(var + 1e-5f);
#pragma unroll
  for (int j = 0; j < 3; ++j) {
    int col = j * 256 + lane * 4;
    float4 wv = *(const float4*)(w + col);
    float4 bv = *(const float4*)(b + col);
    float o0 = (v[j].x - mean) * rs * wv.x + bv.x;
    float o1 = (v[j].y - mean) * rs * wv.y + bv.y;
    float o2 = (v[j].z - mean) * rs * wv.z + bv.z;
    float o3 = (v[j].w - mean) * rs * wv.w + bv.w;
    f16x4 hi = {(f16)o0, (f16)o1, (f16)o2, (f16)o3};
    f16x4 lo = {(f16)(o0 - (float)hi[0]), (f16)(o1 - (float)hi[1]),
                (f16)(o2 - (float)hi[2]), (f16)(o3 - (float)hi[3])};
    *(f16x4*)&yh[row * D_ + col] = hi;
    *(f16x4*)&yl[row * D_ + col] = lo;
  }
}

// -------- weight transpose + f16 hi/lo split: W[K][N] -> Wt[N][K] --------
__global__ __launch_bounds__(256) void transpose_split(
    const float* __restrict__ W, f16* __restrict__ Wh, f16* __restrict__ Wl,
    int Kd, int Nd) {
  __shared__ float t[32][33];
  const int n0 = blockIdx.x * 32, k0 = blockIdx.y * 32;
  const int tx = threadIdx.x & 31, ty = threadIdx.x >> 5;  // 32 x 8
#pragma unroll
  for (int j = 0; j < 4; ++j)
    t[ty + 8 * j][tx] = W[(size_t)(k0 + ty + 8 * j) * Nd + n0 + tx];
  __syncthreads();
#pragma unroll
  for (int j = 0; j < 4; ++j) {
    float v = t[tx][ty + 8 * j];
    f16 hi = (f16)v;
    size_t off = (size_t)(n0 + ty + 8 * j) * Kd + k0 + tx;
    Wh[off] = hi;
    Wl[off] = (f16)(v - (float)hi);
  }
}

// ------- split-f16 MFMA GEMM: C = act(A @ Wt^T + bias) [+C] --------------
// A = Ah+Al (hi/lo f16 planes, [M][K]); Wt = Wh+Wl ([N][K]).
// acc += Ah*Wh + Ah*Wl + Al*Wh  (error ~2^-21 — near-fp32).
// BM=BN=128, BK=32, 256 thr = 4 waves (2x2), wave = 64x64 via 4x4 frags.
// 2-phase double-buffered pipeline (T3/T4): issue next-tile global_load_lds
// BEFORE compute, counted s_waitcnt vmcnt(8) (never 0 in-loop), raw
// s_barriers. Chunk swizzle: gload writes linearly (source lane-permuted
// c_l), ds_read uses physical chunk kg ^ ((fr>>1)&3) -> 2-way banks (free).
template <int ACT, bool RESID, bool OUTSPLIT>
__global__ __launch_bounds__(256) void gemm_split(
    const f16* __restrict__ Ah, const f16* __restrict__ Al,
    const f16* __restrict__ Wh, const f16* __restrict__ Wl,
    const float* __restrict__ bias, float* __restrict__ Cf,
    f16* __restrict__ Ch, f16* __restrict__ Cl, int M, int N, int K) {
  // [buf][plane][row][k] : plane 0=Ah 1=Al 2=Wh 3=Wl ; 64 KB total
  __shared__ __align__(16) f16 S[2][4][128][32];
  const int tid = threadIdx.x;
  const int bm = blockIdx.x * 128, bn = blockIdx.y * 128;
  const int w = tid >> 6, lane = tid & 63;
  const int wm = (w & 1) * 64, wn = (w >> 1) * 64;
  const int fr = lane & 15, kg = lane >> 4;
  f32x4 acc[4][4];
  const f32x4 z = {0.f, 0.f, 0.f, 0.f};
#pragma unroll
  for (int i = 0; i < 4; ++i)
#pragma unroll
    for (int j = 0; j < 4; ++j) acc[i][j] = z;
  const int srow = tid >> 2;                          // dest row (+64 for j=1)
  const int c_l  = (tid & 3) ^ ((tid >> 3) & 3);      // logical k-chunk fetched
  const int cswz = (kg ^ ((fr >> 1) & 3)) * 8;        // physical chunk on read

  auto STAGE = [&](int k0, int buf) {
#pragma unroll
    for (int j = 0; j < 2; ++j) {
      int arow = bm + j * 64 + srow; if (arow >= M) arow = M - 1;  // stores guarded
      int brow = bn + j * 64 + srow;
      size_t aoff = (size_t)arow * K + k0 + c_l * 8;
      size_t boff = (size_t)brow * K + k0 + c_l * 8;
      char* base = (char*)&S[buf][0][0][0] + j * 4096 + w * 1024;
      gload_lds16(Ah + aoff, base);
      gload_lds16(Al + aoff, base + 8192);
      gload_lds16(Wh + boff, base + 16384);
      gload_lds16(Wl + boff, base + 24576);
    }
  };
  auto COMPUTE = [&](int buf) {
    f16x8 ah[4], al[4], bh[4], bl[4];
#pragma unroll
    for (int i = 0; i < 4; ++i) {
      ah[i] = *(const f16x8*)&S[buf][0][wm + i * 16 + fr][cswz];
      al[i] = *(const f16x8*)&S[buf][1][wm + i * 16 + fr][cswz];
      bh[i] = *(const f16x8*)&S[buf][2][wn + i * 16 + fr][cswz];
      bl[i] = *(const f16x8*)&S[buf][3][wn + i * 16 + fr][cswz];
    }
#pragma unroll
    for (int i = 0; i < 4; ++i)
#pragma unroll
      for (int j = 0; j < 4; ++j) {
        acc[i][j] = __builtin_amdgcn_mfma_f32_16x16x32_f16(ah[i], bh[j], acc[i][j], 0, 0, 0);
        acc[i][j] = __builtin_amdgcn_mfma_f32_16x16x32_f16(ah[i], bl[j], acc[i][j], 0, 0, 0);
        acc[i][j] = __builtin_amdgcn_mfma_f32_16x16x32_f16(al[i], bh[j], acc[i][j], 0, 0, 0);
      }
  };

  const int nt = K / 32;
  int cur = 0;
  STAGE(0, 0);
  for (int t = 0; t < nt - 1; ++t) {
    STAGE((t + 1) * 32, cur ^ 1);                       // next tile in flight
    asm volatile("s_waitcnt vmcnt(8)" ::: "memory");    // tile t landed
    __builtin_amdgcn_s_barrier();
    __builtin_amdgcn_sched_barrier(0);
    COMPUTE(cur);
    __builtin_amdgcn_s_barrier();                       // buf reusable
    cur ^= 1;
  }
  asm volatile("s_waitcnt vmcnt(0)" ::: "memory");      // last tile
  __builtin_amdgcn_s_barrier();
  __builtin_amdgcn_sched_barrier(0);
  COMPUTE(cur);

  // epilogue: D[row=(lane>>4)*4+rg][col=lane&15] per fragment (m89 layout)
#pragma unroll
  for (int j = 0; j < 4; ++j) {
    const int gc = bn + wn + j * 16 + fr;
    const float bv = bias[gc];
#pragma unroll
    for (int i = 0; i < 4; ++i) {
#pragma unroll
      for (int rg = 0; rg < 4; ++rg) {
        int gr = bm + wm + i * 16 + kg * 4 + rg;
        if (gr < M) {
          float val = acc[i][j][rg] + bv;
          if (ACT == 1) val = fmaxf(val, 0.f);
          if (ACT == 2) val = 1.f / (1.f + expf(-val));
          size_t off = (size_t)gr * N + gc;
          if (OUTSPLIT) {
            f16 hi = (f16)val;
            Ch[off] = hi;
            Cl[off] = (f16)(val - (float)hi);
          } else {
            if (RESID) val += Cf[off];
            Cf[off] = val;
          }
        }
      }
    }
  }
}

// ---------------- flash attention, fp32 in/compute, f16-split out ---------
// Grid (NB, H, 7): 32 q-rows/block, 4 waves x 8 rows. K-tile + transposed
// V-tile in XOR-swizzled [64][64] fp32 LDS. Online softmax.
__global__ __launch_bounds__(256) void attn_kernel2(
    const float* __restrict__ q, const float* __restrict__ kv,
    f16* __restrict__ oh, f16* __restrict__ ol) {
  __shared__ __align__(16) float Kt[64][64];   // Kt[tok][(d4^(tok&15))*4+i]
  __shared__ __align__(16) float Vt[64][64];   // Vt[d][(tg^(d&15))*4+ti]
  __shared__ __align__(16) float qs[4][8][64];
  __shared__ __align__(16) float ps[4][8][64];
  const int b = blockIdx.x, h = blockIdx.y, qt = blockIdx.z;
  const int tid = threadIdx.x, w = tid >> 6, lane = tid & 63;
  const int n0 = qt * 32;
  float o_r[8], m_r[8], l_r[8];
#pragma unroll
  for (int r = 0; r < 8; ++r) { o_r[r] = 0.f; m_r[r] = -INFINITY; l_r[r] = 0.f; }
#pragma unroll
  for (int r = 0; r < 8; ++r) {
    int n = n0 + w * 8 + r;
    if (n >= NTOK) n = NTOK - 1;       // clamp; stores guarded
    qs[w][r][lane] = q[((size_t)(b * NTOK + n)) * D_ + h * HD_ + lane];
  }
  const int swz = lane & 15;
  const f32x4 z4 = {0.f, 0.f, 0.f, 0.f};
  for (int t = 0; t < 4; ++t) {
    const int t0 = t * 64;
    const int TT = (NTOK - t0) < 64 ? (NTOK - t0) : 64;
    __syncthreads();                   // prior tile fully consumed
    for (int s = tid; s < 1024; s += 256) {
      int tok = s >> 4, d4 = s & 15;
      int tkc = tok < TT ? tok : TT - 1;
      size_t base = ((size_t)(b * NTOK + t0 + tkc) * 2) * D_ + h * HD_ + d4 * 4;
      f32x4 kvec = *(const f32x4*)&kv[base];
      *(f32x4*)&Kt[tok][(d4 ^ (tok & 15)) * 4] = kvec;
      f32x4 vvec = *(const f32x4*)&kv[base + D_];
      int tg = tok >> 2, ti = tok & 3;
#pragma unroll
      for (int i = 0; i < 4; ++i) {
        int dd = d4 * 4 + i;
        Vt[dd][((tg ^ (dd & 15)) << 2) | ti] = vvec[i];
      }
    }
    __syncthreads();
    // ---- scores: lane = token ----
    f32x4 sacc[8];
#pragma unroll
    for (int r = 0; r < 8; ++r) sacc[r] = z4;
#pragma unroll 4
    for (int d4 = 0; d4 < 16; ++d4) {
      f32x4 kvv = *(const f32x4*)&Kt[lane][(d4 ^ swz) * 4];
#pragma unroll
      for (int r = 0; r < 8; ++r) {
        f32x4 qv = *(const f32x4*)&qs[w][r][d4 * 4];
        sacc[r] += kvv * qv;
      }
    }
#pragma unroll
    for (int r = 0; r < 8; ++r) {
      float sv = (sacc[r][0] + sacc[r][1]) + (sacc[r][2] + sacc[r][3]);
      sv *= 0.125f;                    // hd^-0.5
      if (lane >= TT) sv = -INFINITY;
      float tmax = wred_max(sv);
      float newm = fmaxf(m_r[r], tmax);
      float e = __expf(sv - newm);     // -inf -> 0
      float tsum = wred_sum(e);
      float scale = __expf(m_r[r] - newm);
      m_r[r] = newm;
      l_r[r] = l_r[r] * scale + tsum;
      o_r[r] *= scale;
      ps[w][r][lane] = e;
    }
    // ---- PV: lane = d ----
    f32x4 pacc[8];
#pragma unroll
    for (int r = 0; r < 8; ++r) pacc[r] = z4;
    const int nm4 = (TT + 3) >> 2;
#pragma unroll 4
    for (int m4 = 0; m4 < nm4; ++m4) {
      f32x4 vv = *(const f32x4*)&Vt[lane][(m4 ^ swz) * 4];
#pragma unroll
      for (int r = 0; r < 8; ++r) {
        f32x4 pv = *(const f32x4*)&ps[w][r][m4 * 4];
        pacc[r] += vv * pv;
      }
    }
#pragma unroll
    for (int r = 0; r < 8; ++r)
      o_r[r] += (pacc[r][0] + pacc[r][1]) + (pacc[r][2] + pacc[r][3]);
  }
#pragma unroll
  for (int r = 0; r < 8; ++r) {
    int n = n0 + w * 8 + r;
    if (n < NTOK) {
      float val = o_r[r] / l_r[r];
      size_t off = ((size_t)(b * NTOK + n)) * D_ + h * HD_ + lane;
      f16 hi = (f16)val;
      oh[off] = hi;
      ol[off] = (f16)(val - (float)hi);
    }
  }
}

// ---------- gather x[:, :16, :] -> f16 hi/lo planes [2048][768] -----------
__global__ __launch_bounds__(256) void gather_split(
    const float* __restrict__ x, f16* __restrict__ oh, f16* __restrict__ ol) {
  int idx = blockIdx.x * 256 + threadIdx.x;
  if (idx >= B_ * K_ * (D_ / 4)) return;
  int row = idx / (D_ / 4);
  int c4 = (idx % (D_ / 4)) * 4;
  int b = row >> 4, k = row & 15;
  const float* src = x + ((size_t)(b * NTOK + k)) * D_ + c4;
  f16x4 hi, lo;
#pragma unroll
  for (int i = 0; i < 4; ++i) {
    float v = src[i];
    hi[i] = (f16)v;
    lo[i] = (f16)(v - (float)hi[i]);
  }
  *(f16x4*)&oh[(size_t)row * D_ + c4] = hi;
  *(f16x4*)&ol[(size_t)row * D_ + c4] = lo;
}

// ---------------- logits[b,k] = dot(lat[b,k,:], proj[b,:]) ----------------
__global__ __launch_bounds__(64) void logits_kernel(
    const float* __restrict__ lat, const float* __restrict__ proj,
    float* __restrict__ logits) {
  int bk = blockIdx.x;
  int b = bk >> 4;
  int lane = threadIdx.x;
  const float* lr = lat + (size_t)bk * TOK_;
  const float* pr = proj + (size_t)b * TOK_;
  float s = 0.f;
#pragma unroll
  for (int i = 0; i < 8; ++i) s = fmaf(lr[lane + 64 * i], pr[lane + 64 * i], s);
  s = wred_sum(s);
  if (lane == 0) logits[bk] = s;
}

// ---------------- softmax + topk select + normalize (1 wave per b) --------
__global__ __launch_bounds__(64) void select_kernel(
    const float* __restrict__ logits, const float* __restrict__ lat,
    float* __restrict__ out_sel, float* __restrict__ out_numr) {
  const int b = blockIdx.x;
  const int lane = threadIdx.x;
  __shared__ float aw_s[16];
  __shared__ int sel_id_s[8];
  __shared__ int numr_s;
  float v = (lane < 16) ? logits[b * 16 + lane] : -INFINITY;
  float mx = wred_max(v);
  float e = (lane < 16) ? expf(v - mx) : 0.f;
  float sum = wred_sum(e);
  float aw = e / sum;
  if (lane < 16) aw_s[lane] = aw;
  unsigned long long ball = __ballot(lane < 16 && aw > 0.05f);
  int counts = __popcll(ball);
  __syncthreads();
  if (lane == 0) {
    int num_r = counts < 1 ? 1 : (counts > TOPK_ ? TOPK_ : counts);
    numr_s = num_r;
    bool used[16];
#pragma unroll
    for (int i = 0; i < 16; ++i) used[i] = false;
    int sorted_idx[8];
    for (int j = 0; j < 8; ++j) {   // descending top-8 (ties: lowest index)
      float bv = -INFINITY; int bi = 0;
      for (int i = 0; i < 16; ++i)
        if (!used[i] && aw_s[i] > bv) { bv = aw_s[i]; bi = i; }
      used[bi] = true;
      sorted_idx[j] = bi;
    }
    int keys[8];
    for (int j = 0; j < 8; ++j) keys[j] = (j < num_r) ? sorted_idx[j] : (16 + j);
    bool kused[8];
    for (int j = 0; j < 8; ++j) kused[j] = false;
    for (int slot = 0; slot < 8; ++slot) {  // perm = argsort(keys), gather
      int bk = 1 << 30, bj = 0;
      for (int j = 0; j < 8; ++j)
        if (!kused[j] && keys[j] < bk) { bk = keys[j]; bj = j; }
      kused[bj] = true;
      sel_id_s[slot] = sorted_idx[bj];
    }
  }
  __syncthreads();
  for (int j = 0; j < 8; ++j) {
    int id = sel_id_s[j];
    const float* row = lat + ((size_t)b * 16 + id) * TOK_;
    float vals[8];
    float sq = 0.f;
#pragma unroll
    for (int i = 0; i < 8; ++i) {
      vals[i] = row[lane + 64 * i];
      sq = fmaf(vals[i], vals[i], sq);
    }
    sq = wred_sum(sq);
    float inv = 1.f / fmaxf(sqrtf(sq), 1e-12f);
#pragma unroll
    for (int i = 0; i < 8; ++i)
      out_sel[((size_t)b * 8 + j) * TOK_ + lane + 64 * i] = vals[i] * inv;
  }
  if (lane == 0) out_numr[b] = (float)numr_s;
}

// ---------------- host launcher -------------------------------------------
extern "C" void kernel_launch(void* const* d_in, const int* in_sizes, int n_in,
                              void* d_out, int out_size, void* d_ws, size_t ws_size,
                              hipStream_t stream) {
  const float* img_feature_proj = (const float*)d_in[0];
  const float* img_patch_feats  = (const float*)d_in[1];
  const float* templates        = (const float*)d_in[2];
  const float* ln1_w  = (const float*)d_in[3];
  const float* ln1_b  = (const float*)d_in[4];
  const float* q_w    = (const float*)d_in[5];
  const float* q_b    = (const float*)d_in[6];
  const float* kv_w   = (const float*)d_in[7];
  const float* kv_b   = (const float*)d_in[8];
  const float* proj_w = (const float*)d_in[9];
  const float* proj_b = (const float*)d_in[10];
  const float* ln2_w  = (const float*)d_in[11];
  const float* ln2_b  = (const float*)d_in[12];
  const float* fc1_w  = (const float*)d_in[13];
  const float* fc1_b  = (const float*)d_in[14];
  const float* fc2_w  = (const float*)d_in[15];
  const float* fc2_b  = (const float*)d_in[16];
  const float* att_fc_w = (const float*)d_in[17];
  const float* att_fc_b = (const float*)d_in[18];

  // ---- fixed workspace (~115 MB) ----
  char* ws = (char*)d_ws;
  const size_t XB = (size_t)MROWS * D_ * 4;              // 83,755,008 B
  float* x_f = (float*)ws;  ws += XB;                    // residual fp32
  auto alloc_f16 = [&](size_t n) { f16* p = (f16*)ws; ws += n * 2; return p; };
  f16* wq_h  = alloc_f16((size_t)768 * 768);
  f16* wq_l  = alloc_f16((size_t)768 * 768);
  f16* wkv_h = alloc_f16((size_t)1536 * 768);
  f16* wkv_l = alloc_f16((size_t)1536 * 768);
  f16* wp_h  = alloc_f16((size_t)768 * 768);
  f16* wp_l  = alloc_f16((size_t)768 * 768);
  f16* wf1_h = alloc_f16((size_t)1536 * 768);
  f16* wf1_l = alloc_f16((size_t)1536 * 768);
  f16* wf2_h = alloc_f16((size_t)768 * 1536);
  f16* wf2_l = alloc_f16((size_t)768 * 1536);
  f16* awt_h = alloc_f16((size_t)512 * 768);
  f16* awt_l = alloc_f16((size_t)512 * 768);
  f16* lat_h = alloc_f16((size_t)2048 * 768);
  f16* lat_l = alloc_f16((size_t)2048 * 768);
  float* lat    = (float*)ws; ws += (size_t)2048 * 512 * 4;
  float* logits = (float*)ws; ws += 8192;
  const size_t fixed_bytes = (size_t)(ws - (char*)d_ws);

  // ---- adaptive batch-chunk: h planes(4B) + q_f(4B) + kv_f(8B) per elem
  int NB = B_;
  while (NB > 1) {
    size_t CHE = (size_t)NB * NTOK * D_;
    if (fixed_bytes + 16 * CHE <= ws_size) break;
    NB >>= 1;
  }
  const size_t CHE = (size_t)NB * NTOK * D_;
  f16* h_h = (f16*)ws;                         // CHE f16
  f16* h_l = h_h + CHE;                        // CHE f16
  float* q_f  = (float*)(h_l + CHE);           // CHE f32
  float* kv_f = q_f + CHE;                     // 2*CHE f32
  f16* fc1o_h = (f16*)q_f;                     // alias: 2*CHE f16
  f16* fc1o_l = (f16*)kv_f;                    // alias: 2*CHE f16

  // ---- concat ----
  {
    size_t total = (size_t)MROWS * (D_ / 4);
    concat_kernel<<<(unsigned)((total + 255) / 256), 256, 0, stream>>>(
        templates, img_patch_feats, x_f);
  }
  transpose_split<<<dim3(16, 24), 256, 0, stream>>>(att_fc_w, awt_h, awt_l, 768, 512);

  const int nchunks = B_ / NB;
  for (int l = 0; l < L_; ++l) {
    transpose_split<<<dim3(24, 24), 256, 0, stream>>>(q_w + (size_t)l * 768 * 768, wq_h, wq_l, 768, 768);
    transpose_split<<<dim3(48, 24), 256, 0, stream>>>(kv_w + (size_t)l * 768 * 1536, wkv_h, wkv_l, 768, 1536);
    transpose_split<<<dim3(24, 24), 256, 0, stream>>>(proj_w + (size_t)l * 768 * 768, wp_h, wp_l, 768, 768);
    transpose_split<<<dim3(48, 24), 256, 0, stream>>>(fc1_w + (size_t)l * 768 * 1536, wf1_h, wf1_l, 768, 1536);
    transpose_split<<<dim3(24, 48), 256, 0, stream>>>(fc2_w + (size_t)l * 1536 * 768, wf2_h, wf2_l, 1536, 768);
    for (int c = 0; c < nchunks; ++c) {
      const int b0 = c * NB;
      const int Rc = NB * NTOK;
      const int mt = (Rc + 127) / 128;
      float* xc = x_f + (size_t)b0 * NTOK * D_;
      ln_split_kernel<<<Rc, 64, 0, stream>>>(xc, ln1_w + l * D_, ln1_b + l * D_, h_h, h_l);
      gemm_split<0, false, false><<<dim3(mt, 6), 256, 0, stream>>>(
          h_h, h_l, wq_h, wq_l, q_b + l * D_, q_f, nullptr, nullptr, Rc, 768, 768);
      gemm_split<0, false, false><<<dim3(mt, 12), 256, 0, stream>>>(
          h_h, h_l, wkv_h, wkv_l, kv_b + l * 1536, kv_f, nullptr, nullptr, Rc, 1536, 768);
      attn_kernel2<<<dim3(NB, H_, 7), 256, 0, stream>>>(q_f, kv_f, h_h, h_l);
      gemm_split<0, true, false><<<dim3(mt, 6), 256, 0, stream>>>(
          h_h, h_l, wp_h, wp_l, proj_b + l * D_, xc, nullptr, nullptr, Rc, 768, 768);
      ln_split_kernel<<<Rc, 64, 0, stream>>>(xc, ln2_w + l * D_, ln2_b + l * D_, h_h, h_l);
      gemm_split<1, false, true><<<dim3(mt, 12), 256, 0, stream>>>(
          h_h, h_l, wf1_h, wf1_l, fc1_b + l * 1536, nullptr, fc1o_h, fc1o_l, Rc, 1536, 768);
      gemm_split<0, true, false><<<dim3(mt, 6), 256, 0, stream>>>(
          fc1o_h, fc1o_l, wf2_h, wf2_l, fc2_b + l * D_, xc, nullptr, nullptr, Rc, 768, 1536);
    }
  }

  gather_split<<<(B_ * K_ * (D_ / 4) + 255) / 256, 256, 0, stream>>>(x_f, lat_h, lat_l);
  gemm_split<2, false, false><<<dim3(16, 4), 256, 0, stream>>>(
      lat_h, lat_l, awt_h, awt_l, att_fc_b, lat, nullptr, nullptr, B_ * K_, TOK_, 768);

  logits_kernel<<<B_ * K_, 64, 0, stream>>>(lat, img_feature_proj, logits);
  select_kernel<<<B_, 64, 0, stream>>>(logits, lat, (float*)d_out,
                                       (float*)d_out + (size_t)B_ * TOPK_ * TOK_);
}

// Round 8
// 3024.372 us; speedup vs baseline: 1.4017x; 1.3023x over previous
//
#include <hip/hip_runtime.h>
#include <math.h>

// Problem constants
#define B_    128
#define P_    197
#define D_    768
#define TOK_  512
#define K_    16
#define TOPK_ 8
#define L_    2
#define H_    12
#define HD_   64
#define NTOK  213            // K_ + P_
#define MROWS (B_ * NTOK)    // 27264

typedef _Float16 f16;
typedef __attribute__((ext_vector_type(8))) _Float16 f16x8;
typedef __attribute__((ext_vector_type(4))) _Float16 f16x4;
typedef __attribute__((ext_vector_type(4))) float f32x4;

__device__ __forceinline__ void gload_lds16(const void* g, void* l) {
  __builtin_amdgcn_global_load_lds(
      (const __attribute__((address_space(1))) unsigned int*)g,
      (__attribute__((address_space(3))) unsigned int*)l, 16, 0, 0);
}

__device__ __forceinline__ float wred_sum(float v) {
#pragma unroll
  for (int o = 32; o > 0; o >>= 1) v += __shfl_xor(v, o);
  return v;
}
__device__ __forceinline__ float wred_max(float v) {
#pragma unroll
  for (int o = 32; o > 0; o >>= 1) v = fmaxf(v, __shfl_xor(v, o));
  return v;
}
// 16-lane-group reductions (rows of an MFMA C-frag live on 16 lanes)
__device__ __forceinline__ float red16_max(float v) {
#pragma unroll
  for (int o = 8; o > 0; o >>= 1) v = fmaxf(v, __shfl_xor(v, o));
  return v;
}
__device__ __forceinline__ float red16_sum(float v) {
#pragma unroll
  for (int o = 8; o > 0; o >>= 1) v += __shfl_xor(v, o);
  return v;
}

// ---------------- concat: x = [templates broadcast | img_patch_feats] ----
__global__ __launch_bounds__(256) void concat_kernel(
    const float* __restrict__ tpl, const float* __restrict__ patches,
    float* __restrict__ x) {
  size_t i = (size_t)blockIdx.x * 256 + threadIdx.x;  // one float4 each
  const size_t total = (size_t)MROWS * (D_ / 4);
  if (i >= total) return;
  size_t row = i / (D_ / 4);
  int c = (int)(i % (D_ / 4)) * 4;
  size_t b = row / NTOK;
  int n = (int)(row % NTOK);
  float4 v;
  if (n < K_) v = *(const float4*)(tpl + (size_t)n * D_ + c);
  else        v = *(const float4*)(patches + ((size_t)b * P_ + (n - K_)) * D_ + c);
  *(float4*)(x + row * D_ + c) = v;
}

// ---------------- LayerNorm: one wave per row, f16 hi/lo split out --------
__global__ __launch_bounds__(64) void ln_split_kernel(
    const float* __restrict__ x, const float* __restrict__ w,
    const float* __restrict__ b, f16* __restrict__ yh, f16* __restrict__ yl) {
  size_t row = blockIdx.x;
  int lane = threadIdx.x;
  const float* xr = x + row * D_;
  float4 v[3];
#pragma unroll
  for (int j = 0; j < 3; ++j) v[j] = *(const float4*)(xr + j * 256 + lane * 4);
  float s = 0.f, sq = 0.f;
#pragma unroll
  for (int j = 0; j < 3; ++j) {
    s += v[j].x + v[j].y + v[j].z + v[j].w;
    sq = fmaf(v[j].x, v[j].x, sq); sq = fmaf(v[j].y, v[j].y, sq);
    sq = fmaf(v[j].z, v[j].z, sq); sq = fmaf(v[j].w, v[j].w, sq);
  }
#pragma unroll
  for (int o = 32; o > 0; o >>= 1) { s += __shfl_xor(s, o); sq += __shfl_xor(sq, o); }
  float mean = s * (1.f / D_);
  float var = sq * (1.f / D_) - mean * mean;
  float rs = rsqrtf(var + 1e-5f);
#pragma unroll
  for (int j = 0; j < 3; ++j) {
    int col = j * 256 + lane * 4;
    float4 wv = *(const float4*)(w + col);
    float4 bv = *(const float4*)(b + col);
    float o0 = (v[j].x - mean) * rs * wv.x + bv.x;
    float o1 = (v[j].y - mean) * rs * wv.y + bv.y;
    float o2 = (v[j].z - mean) * rs * wv.z + bv.z;
    float o3 = (v[j].w - mean) * rs * wv.w + bv.w;
    f16x4 hi = {(f16)o0, (f16)o1, (f16)o2, (f16)o3};
    f16x4 lo = {(f16)(o0 - (float)hi[0]), (f16)(o1 - (float)hi[1]),
                (f16)(o2 - (float)hi[2]), (f16)(o3 - (float)hi[3])};
    *(f16x4*)&yh[row * D_ + col] = hi;
    *(f16x4*)&yl[row * D_ + col] = lo;
  }
}

// -------- weight transpose + f16 hi/lo split: W[K][N] -> Wt[N][K] --------
__global__ __launch_bounds__(256) void transpose_split(
    const float* __restrict__ W, f16* __restrict__ Wh, f16* __restrict__ Wl,
    int Kd, int Nd) {
  __shared__ float t[32][33];
  const int n0 = blockIdx.x * 32, k0 = blockIdx.y * 32;
  const int tx = threadIdx.x & 31, ty = threadIdx.x >> 5;  // 32 x 8
#pragma unroll
  for (int j = 0; j < 4; ++j)
    t[ty + 8 * j][tx] = W[(size_t)(k0 + ty + 8 * j) * Nd + n0 + tx];
  __syncthreads();
#pragma unroll
  for (int j = 0; j < 4; ++j) {
    float v = t[tx][ty + 8 * j];
    f16 hi = (f16)v;
    size_t off = (size_t)(n0 + ty + 8 * j) * Kd + k0 + tx;
    Wh[off] = hi;
    Wl[off] = (f16)(v - (float)hi);
  }
}

// ------- split-f16 MFMA GEMM: C = act(A @ Wt^T + bias) [+C] --------------
// (unchanged from R7 — 2-phase dbuf, counted vmcnt, chunk swizzle)
template <int ACT, bool RESID, bool OUTSPLIT>
__global__ __launch_bounds__(256) void gemm_split(
    const f16* __restrict__ Ah, const f16* __restrict__ Al,
    const f16* __restrict__ Wh, const f16* __restrict__ Wl,
    const float* __restrict__ bias, float* __restrict__ Cf,
    f16* __restrict__ Ch, f16* __restrict__ Cl, int M, int N, int K) {
  __shared__ __align__(16) f16 S[2][4][128][32];
  const int tid = threadIdx.x;
  const int bm = blockIdx.x * 128, bn = blockIdx.y * 128;
  const int w = tid >> 6, lane = tid & 63;
  const int wm = (w & 1) * 64, wn = (w >> 1) * 64;
  const int fr = lane & 15, kg = lane >> 4;
  f32x4 acc[4][4];
  const f32x4 z = {0.f, 0.f, 0.f, 0.f};
#pragma unroll
  for (int i = 0; i < 4; ++i)
#pragma unroll
    for (int j = 0; j < 4; ++j) acc[i][j] = z;
  const int srow = tid >> 2;
  const int c_l  = (tid & 3) ^ ((tid >> 3) & 3);
  const int cswz = (kg ^ ((fr >> 1) & 3)) * 8;

  auto STAGE = [&](int k0, int buf) {
#pragma unroll
    for (int j = 0; j < 2; ++j) {
      int arow = bm + j * 64 + srow; if (arow >= M) arow = M - 1;
      int brow = bn + j * 64 + srow;
      size_t aoff = (size_t)arow * K + k0 + c_l * 8;
      size_t boff = (size_t)brow * K + k0 + c_l * 8;
      char* base = (char*)&S[buf][0][0][0] + j * 4096 + w * 1024;
      gload_lds16(Ah + aoff, base);
      gload_lds16(Al + aoff, base + 8192);
      gload_lds16(Wh + boff, base + 16384);
      gload_lds16(Wl + boff, base + 24576);
    }
  };
  auto COMPUTE = [&](int buf) {
    f16x8 ah[4], al[4], bh[4], bl[4];
#pragma unroll
    for (int i = 0; i < 4; ++i) {
      ah[i] = *(const f16x8*)&S[buf][0][wm + i * 16 + fr][cswz];
      al[i] = *(const f16x8*)&S[buf][1][wm + i * 16 + fr][cswz];
      bh[i] = *(const f16x8*)&S[buf][2][wn + i * 16 + fr][cswz];
      bl[i] = *(const f16x8*)&S[buf][3][wn + i * 16 + fr][cswz];
    }
#pragma unroll
    for (int i = 0; i < 4; ++i)
#pragma unroll
      for (int j = 0; j < 4; ++j) {
        acc[i][j] = __builtin_amdgcn_mfma_f32_16x16x32_f16(ah[i], bh[j], acc[i][j], 0, 0, 0);
        acc[i][j] = __builtin_amdgcn_mfma_f32_16x16x32_f16(ah[i], bl[j], acc[i][j], 0, 0, 0);
        acc[i][j] = __builtin_amdgcn_mfma_f32_16x16x32_f16(al[i], bh[j], acc[i][j], 0, 0, 0);
      }
  };

  const int nt = K / 32;
  int cur = 0;
  STAGE(0, 0);
  for (int t = 0; t < nt - 1; ++t) {
    STAGE((t + 1) * 32, cur ^ 1);
    asm volatile("s_waitcnt vmcnt(8)" ::: "memory");
    __builtin_amdgcn_s_barrier();
    __builtin_amdgcn_sched_barrier(0);
    COMPUTE(cur);
    __builtin_amdgcn_s_barrier();
    cur ^= 1;
  }
  asm volatile("s_waitcnt vmcnt(0)" ::: "memory");
  __builtin_amdgcn_s_barrier();
  __builtin_amdgcn_sched_barrier(0);
  COMPUTE(cur);

#pragma unroll
  for (int j = 0; j < 4; ++j) {
    const int gc = bn + wn + j * 16 + fr;
    const float bv = bias[gc];
#pragma unroll
    for (int i = 0; i < 4; ++i) {
#pragma unroll
      for (int rg = 0; rg < 4; ++rg) {
        int gr = bm + wm + i * 16 + kg * 4 + rg;
        if (gr < M) {
          float val = acc[i][j][rg] + bv;
          if (ACT == 1) val = fmaxf(val, 0.f);
          if (ACT == 2) val = 1.f / (1.f + expf(-val));
          size_t off = (size_t)gr * N + gc;
          if (OUTSPLIT) {
            f16 hi = (f16)val;
            Ch[off] = hi;
            Cl[off] = (f16)(val - (float)hi);
          } else {
            if (RESID) val += Cf[off];
            Cf[off] = val;
          }
        }
      }
    }
  }
}

// ---------------- MFMA flash attention, split-f16 3-pass ------------------
// Grid (NB, H, 2): 128 q-rows/block (4 waves x 32), K/V in 64-token tiles.
// K staged via global_load_lds (chunk^(row&7) swizzle via inverse-permuted
// source); V transpose-staged [d][tok] with chunk^(d&7); S = QK^T MFMA
// (m89 C-layout), online softmax (16-lane shfl row-reduce), P split hi/lo
// -> LDS -> PV MFMA. LDS 64 KB -> 2 blocks/CU.
__global__ __launch_bounds__(256) void attn_mfma(
    const f16* __restrict__ Qh, const f16* __restrict__ Ql,
    const f16* __restrict__ KVh, const f16* __restrict__ KVl,
    f16* __restrict__ Oh, f16* __restrict__ Ol) {
  __shared__ __align__(16) f16 Ksh[64][64];
  __shared__ __align__(16) f16 Ksl[64][64];
  __shared__ __align__(16) f16 Vsh[64][64];
  __shared__ __align__(16) f16 Vsl[64][64];
  __shared__ __align__(16) f16 Psh[4][32][64];
  __shared__ __align__(16) f16 Psl[4][32][64];
  const int b = blockIdx.x, h = blockIdx.y, zb = blockIdx.z;
  const int tid = threadIdx.x, w = tid >> 6, lane = tid & 63;
  const int fr = lane & 15, kg = lane >> 4;
  const int qbase = zb * 128 + w * 32;
  const size_t rowbase = (size_t)b * NTOK;
  const int hoff = h * HD_;
  const f32x4 z4 = {0.f, 0.f, 0.f, 0.f};

  // Q fragments in registers (persist across K-tiles)
  f16x8 qfh[2][2], qfl[2][2];
#pragma unroll
  for (int mf = 0; mf < 2; ++mf) {
    int qr = qbase + mf * 16 + fr; if (qr >= NTOK) qr = NTOK - 1;
    const size_t ro = (rowbase + qr) * D_ + hoff;
#pragma unroll
    for (int ks = 0; ks < 2; ++ks) {
      qfh[mf][ks] = *(const f16x8*)&Qh[ro + ks * 32 + kg * 8];
      qfl[mf][ks] = *(const f16x8*)&Ql[ro + ks * 32 + kg * 8];
    }
  }

  f32x4 oacc[2][4];
#pragma unroll
  for (int mf = 0; mf < 2; ++mf)
#pragma unroll
    for (int df = 0; df < 4; ++df) oacc[mf][df] = z4;
  float m_r[2][4], l_r[2][4];
#pragma unroll
  for (int mf = 0; mf < 2; ++mf)
#pragma unroll
    for (int rg = 0; rg < 4; ++rg) { m_r[mf][rg] = -INFINITY; l_r[mf][rg] = 0.f; }

  for (int t = 0; t < 4; ++t) {
    const int t0 = t * 64;
    __syncthreads();                      // prior tile fully consumed
    // ---- stage K planes (gload, swizzled source) ----
#pragma unroll
    for (int s = 0; s < 2; ++s) {
      int slot = tid + s * 256;
      int trow = slot >> 3, pch = slot & 7;
      int lch = pch ^ (trow & 7);
      int tok = t0 + trow; if (tok >= NTOK) tok = NTOK - 1;
      size_t src = (rowbase + tok) * (size_t)(2 * D_) + hoff + lch * 8;
      gload_lds16(KVh + src, (char*)&Ksh[0][0] + s * 4096 + w * 1024);
      gload_lds16(KVl + src, (char*)&Ksl[0][0] + s * 4096 + w * 1024);
    }
    // ---- stage V transposed [d][tok], chunk^(d&7) swizzle ----
    {
      int tloc = tid & 63, dg = tid >> 6;
      int tok = t0 + tloc; if (tok >= NTOK) tok = NTOK - 1;
      size_t src = (rowbase + tok) * (size_t)(2 * D_) + D_ + hoff + dg * 16;
      f16x8 v0h = *(const f16x8*)&KVh[src];
      f16x8 v1h = *(const f16x8*)&KVh[src + 8];
      f16x8 v0l = *(const f16x8*)&KVl[src];
      f16x8 v1l = *(const f16x8*)&KVl[src + 8];
      int ch = tloc >> 3, pos = tloc & 7;
#pragma unroll
      for (int i = 0; i < 8; ++i) {
        int d0 = dg * 16 + i, d1 = d0 + 8;
        Vsh[d0][((ch ^ (d0 & 7)) << 3) | pos] = v0h[i];
        Vsh[d1][((ch ^ (d1 & 7)) << 3) | pos] = v1h[i];
        Vsl[d0][((ch ^ (d0 & 7)) << 3) | pos] = v0l[i];
        Vsl[d1][((ch ^ (d1 & 7)) << 3) | pos] = v1l[i];
      }
    }
    __syncthreads();                      // staging visible
    // ---- S = QK^T (3-pass split) ----
    f16x8 kbh[4][2], kbl[4][2];
#pragma unroll
    for (int nf = 0; nf < 4; ++nf)
#pragma unroll
      for (int ks = 0; ks < 2; ++ks) {
        int phys = (((ks * 4 + kg) ^ (fr & 7))) * 8;
        kbh[nf][ks] = *(const f16x8*)&Ksh[nf * 16 + fr][phys];
        kbl[nf][ks] = *(const f16x8*)&Ksl[nf * 16 + fr][phys];
      }
    f32x4 sacc[2][4];
#pragma unroll
    for (int mf = 0; mf < 2; ++mf)
#pragma unroll
      for (int nf = 0; nf < 4; ++nf) sacc[mf][nf] = z4;
#pragma unroll
    for (int ks = 0; ks < 2; ++ks)
#pragma unroll
      for (int mf = 0; mf < 2; ++mf)
#pragma unroll
        for (int nf = 0; nf < 4; ++nf) {
          sacc[mf][nf] = __builtin_amdgcn_mfma_f32_16x16x32_f16(qfh[mf][ks], kbh[nf][ks], sacc[mf][nf], 0, 0, 0);
          sacc[mf][nf] = __builtin_amdgcn_mfma_f32_16x16x32_f16(qfh[mf][ks], kbl[nf][ks], sacc[mf][nf], 0, 0, 0);
          sacc[mf][nf] = __builtin_amdgcn_mfma_f32_16x16x32_f16(qfl[mf][ks], kbh[nf][ks], sacc[mf][nf], 0, 0, 0);
        }
    // ---- scale + mask ----
#pragma unroll
    for (int nf = 0; nf < 4; ++nf) {
      bool valid = (t0 + nf * 16 + fr) < NTOK;
#pragma unroll
      for (int mf = 0; mf < 2; ++mf)
#pragma unroll
        for (int rg = 0; rg < 4; ++rg)
          sacc[mf][nf][rg] = valid ? sacc[mf][nf][rg] * 0.125f : -INFINITY;
    }
    // ---- online softmax + P hi/lo -> LDS ----
#pragma unroll
    for (int mf = 0; mf < 2; ++mf) {
      float scl[4];
#pragma unroll
      for (int rg = 0; rg < 4; ++rg) {
        float mx = fmaxf(fmaxf(sacc[mf][0][rg], sacc[mf][1][rg]),
                         fmaxf(sacc[mf][2][rg], sacc[mf][3][rg]));
        mx = red16_max(mx);
        float nm = fmaxf(m_r[mf][rg], mx);
        scl[rg] = __expf(m_r[mf][rg] - nm);
        m_r[mf][rg] = nm;
        float ts = 0.f;
        int qlc = mf * 16 + kg * 4 + rg;
#pragma unroll
        for (int nf = 0; nf < 4; ++nf) {
          float p = __expf(sacc[mf][nf][rg] - nm);
          ts += p;
          f16 ph = (f16)p;
          int tl = nf * 16 + fr;
          int off = (((tl >> 3) ^ (qlc & 7)) << 3) | (tl & 7);
          Psh[w][qlc][off] = ph;
          Psl[w][qlc][off] = (f16)(p - (float)ph);
        }
        ts = red16_sum(ts);
        l_r[mf][rg] = l_r[mf][rg] * scl[rg] + ts;
      }
#pragma unroll
      for (int df = 0; df < 4; ++df)
#pragma unroll
        for (int rg = 0; rg < 4; ++rg)
          oacc[mf][df][rg] *= scl[rg];
    }
    // ---- O += P @ V (3-pass split) ----
    f16x8 vbh[4][2], vbl[4][2];
#pragma unroll
    for (int df = 0; df < 4; ++df)
#pragma unroll
      for (int ks = 0; ks < 2; ++ks) {
        int phys = (((ks * 4 + kg) ^ (fr & 7))) * 8;
        vbh[df][ks] = *(const f16x8*)&Vsh[df * 16 + fr][phys];
        vbl[df][ks] = *(const f16x8*)&Vsl[df * 16 + fr][phys];
      }
    f16x8 pah[2][2], pal[2][2];
#pragma unroll
    for (int mf = 0; mf < 2; ++mf)
#pragma unroll
      for (int ks = 0; ks < 2; ++ks) {
        int phys = (((ks * 4 + kg) ^ (fr & 7))) * 8;
        pah[mf][ks] = *(const f16x8*)&Psh[w][mf * 16 + fr][phys];
        pal[mf][ks] = *(const f16x8*)&Psl[w][mf * 16 + fr][phys];
      }
#pragma unroll
    for (int ks = 0; ks < 2; ++ks)
#pragma unroll
      for (int mf = 0; mf < 2; ++mf)
#pragma unroll
        for (int df = 0; df < 4; ++df) {
          oacc[mf][df] = __builtin_amdgcn_mfma_f32_16x16x32_f16(pah[mf][ks], vbh[df][ks], oacc[mf][df], 0, 0, 0);
          oacc[mf][df] = __builtin_amdgcn_mfma_f32_16x16x32_f16(pah[mf][ks], vbl[df][ks], oacc[mf][df], 0, 0, 0);
          oacc[mf][df] = __builtin_amdgcn_mfma_f32_16x16x32_f16(pal[mf][ks], vbh[df][ks], oacc[mf][df], 0, 0, 0);
        }
  }
  // ---- finalize + store f16 hi/lo ----
#pragma unroll
  for (int mf = 0; mf < 2; ++mf)
#pragma unroll
    for (int rg = 0; rg < 4; ++rg) {
      int qr = qbase + mf * 16 + kg * 4 + rg;
      if (qr < NTOK) {
        float inv = 1.f / l_r[mf][rg];
        size_t ro = (rowbase + qr) * D_ + hoff;
#pragma unroll
        for (int df = 0; df < 4; ++df) {
          float val = oacc[mf][df][rg] * inv;
          f16 hi = (f16)val;
          Oh[ro + df * 16 + fr] = hi;
          Ol[ro + df * 16 + fr] = (f16)(val - (float)hi);
        }
      }
    }
}

// ---------- gather x[:, :16, :] -> f16 hi/lo planes [2048][768] -----------
__global__ __launch_bounds__(256) void gather_split(
    const float* __restrict__ x, f16* __restrict__ oh, f16* __restrict__ ol) {
  int idx = blockIdx.x * 256 + threadIdx.x;
  if (idx >= B_ * K_ * (D_ / 4)) return;
  int row = idx / (D_ / 4);
  int c4 = (idx % (D_ / 4)) * 4;
  int b = row >> 4, k = row & 15;
  const float* src = x + ((size_t)(b * NTOK + k)) * D_ + c4;
  f16x4 hi, lo;
#pragma unroll
  for (int i = 0; i < 4; ++i) {
    float v = src[i];
    hi[i] = (f16)v;
    lo[i] = (f16)(v - (float)hi[i]);
  }
  *(f16x4*)&oh[(size_t)row * D_ + c4] = hi;
  *(f16x4*)&ol[(size_t)row * D_ + c4] = lo;
}

// ---------------- logits[b,k] = dot(lat[b,k,:], proj[b,:]) ----------------
__global__ __launch_bounds__(64) void logits_kernel(
    const float* __restrict__ lat, const float* __restrict__ proj,
    float* __restrict__ logits) {
  int bk = blockIdx.x;
  int b = bk >> 4;
  int lane = threadIdx.x;
  const float* lr = lat + (size_t)bk * TOK_;
  const float* pr = proj + (size_t)b * TOK_;
  float s = 0.f;
#pragma unroll
  for (int i = 0; i < 8; ++i) s = fmaf(lr[lane + 64 * i], pr[lane + 64 * i], s);
  s = wred_sum(s);
  if (lane == 0) logits[bk] = s;
}

// ---------------- softmax + topk select + normalize (1 wave per b) --------
__global__ __launch_bounds__(64) void select_kernel(
    const float* __restrict__ logits, const float* __restrict__ lat,
    float* __restrict__ out_sel, float* __restrict__ out_numr) {
  const int b = blockIdx.x;
  const int lane = threadIdx.x;
  __shared__ float aw_s[16];
  __shared__ int sel_id_s[8];
  __shared__ int numr_s;
  float v = (lane < 16) ? logits[b * 16 + lane] : -INFINITY;
  float mx = wred_max(v);
  float e = (lane < 16) ? expf(v - mx) : 0.f;
  float sum = wred_sum(e);
  float aw = e / sum;
  if (lane < 16) aw_s[lane] = aw;
  unsigned long long ball = __ballot(lane < 16 && aw > 0.05f);
  int counts = __popcll(ball);
  __syncthreads();
  if (lane == 0) {
    int num_r = counts < 1 ? 1 : (counts > TOPK_ ? TOPK_ : counts);
    numr_s = num_r;
    bool used[16];
#pragma unroll
    for (int i = 0; i < 16; ++i) used[i] = false;
    int sorted_idx[8];
    for (int j = 0; j < 8; ++j) {   // descending top-8 (ties: lowest index)
      float bv = -INFINITY; int bi = 0;
      for (int i = 0; i < 16; ++i)
        if (!used[i] && aw_s[i] > bv) { bv = aw_s[i]; bi = i; }
      used[bi] = true;
      sorted_idx[j] = bi;
    }
    int keys[8];
    for (int j = 0; j < 8; ++j) keys[j] = (j < num_r) ? sorted_idx[j] : (16 + j);
    bool kused[8];
    for (int j = 0; j < 8; ++j) kused[j] = false;
    for (int slot = 0; slot < 8; ++slot) {  // perm = argsort(keys), gather
      int bk = 1 << 30, bj = 0;
      for (int j = 0; j < 8; ++j)
        if (!kused[j] && keys[j] < bk) { bk = keys[j]; bj = j; }
      kused[bj] = true;
      sel_id_s[slot] = sorted_idx[bj];
    }
  }
  __syncthreads();
  for (int j = 0; j < 8; ++j) {
    int id = sel_id_s[j];
    const float* row = lat + ((size_t)b * 16 + id) * TOK_;
    float vals[8];
    float sq = 0.f;
#pragma unroll
    for (int i = 0; i < 8; ++i) {
      vals[i] = row[lane + 64 * i];
      sq = fmaf(vals[i], vals[i], sq);
    }
    sq = wred_sum(sq);
    float inv = 1.f / fmaxf(sqrtf(sq), 1e-12f);
#pragma unroll
    for (int i = 0; i < 8; ++i)
      out_sel[((size_t)b * 8 + j) * TOK_ + lane + 64 * i] = vals[i] * inv;
  }
  if (lane == 0) out_numr[b] = (float)numr_s;
}

// ---------------- host launcher -------------------------------------------
extern "C" void kernel_launch(void* const* d_in, const int* in_sizes, int n_in,
                              void* d_out, int out_size, void* d_ws, size_t ws_size,
                              hipStream_t stream) {
  const float* img_feature_proj = (const float*)d_in[0];
  const float* img_patch_feats  = (const float*)d_in[1];
  const float* templates        = (const float*)d_in[2];
  const float* ln1_w  = (const float*)d_in[3];
  const float* ln1_b  = (const float*)d_in[4];
  const float* q_w    = (const float*)d_in[5];
  const float* q_b    = (const float*)d_in[6];
  const float* kv_w   = (const float*)d_in[7];
  const float* kv_b   = (const float*)d_in[8];
  const float* proj_w = (const float*)d_in[9];
  const float* proj_b = (const float*)d_in[10];
  const float* ln2_w  = (const float*)d_in[11];
  const float* ln2_b  = (const float*)d_in[12];
  const float* fc1_w  = (const float*)d_in[13];
  const float* fc1_b  = (const float*)d_in[14];
  const float* fc2_w  = (const float*)d_in[15];
  const float* fc2_b  = (const float*)d_in[16];
  const float* att_fc_w = (const float*)d_in[17];
  const float* att_fc_b = (const float*)d_in[18];

  // ---- fixed workspace (~115 MB) ----
  char* ws = (char*)d_ws;
  const size_t XB = (size_t)MROWS * D_ * 4;              // 83,755,008 B
  float* x_f = (float*)ws;  ws += XB;                    // residual fp32
  auto alloc_f16 = [&](size_t n) { f16* p = (f16*)ws; ws += n * 2; return p; };
  f16* wq_h  = alloc_f16((size_t)768 * 768);
  f16* wq_l  = alloc_f16((size_t)768 * 768);
  f16* wkv_h = alloc_f16((size_t)1536 * 768);
  f16* wkv_l = alloc_f16((size_t)1536 * 768);
  f16* wp_h  = alloc_f16((size_t)768 * 768);
  f16* wp_l  = alloc_f16((size_t)768 * 768);
  f16* wf1_h = alloc_f16((size_t)1536 * 768);
  f16* wf1_l = alloc_f16((size_t)1536 * 768);
  f16* wf2_h = alloc_f16((size_t)768 * 1536);
  f16* wf2_l = alloc_f16((size_t)768 * 1536);
  f16* awt_h = alloc_f16((size_t)512 * 768);
  f16* awt_l = alloc_f16((size_t)512 * 768);
  f16* lat_h = alloc_f16((size_t)2048 * 768);
  f16* lat_l = alloc_f16((size_t)2048 * 768);
  float* lat    = (float*)ws; ws += (size_t)2048 * 512 * 4;
  float* logits = (float*)ws; ws += 8192;
  const size_t fixed_bytes = (size_t)(ws - (char*)d_ws);

  // ---- adaptive batch-chunk: h(4B) + q planes(4B) + kv planes(8B)/elem ----
  int NB = B_;
  while (NB > 1) {
    size_t CHE = (size_t)NB * NTOK * D_;
    if (fixed_bytes + 16 * CHE <= ws_size) break;
    NB >>= 1;
  }
  const size_t CHE = (size_t)NB * NTOK * D_;
  f16* h_h = (f16*)ws;                   // CHE
  f16* h_l = h_h + CHE;                  // CHE
  f16* qh  = h_l + CHE;                  // CHE
  f16* ql  = qh + CHE;                   // CHE
  f16* kvh = ql + CHE;                   // 2*CHE
  f16* kvl = kvh + 2 * CHE;              // 2*CHE
  f16* fc1o_h = qh;                      // alias: 2*CHE (spans qh+ql)
  f16* fc1o_l = kvh;                     // alias: 2*CHE

  // ---- concat ----
  {
    size_t total = (size_t)MROWS * (D_ / 4);
    concat_kernel<<<(unsigned)((total + 255) / 256), 256, 0, stream>>>(
        templates, img_patch_feats, x_f);
  }
  transpose_split<<<dim3(16, 24), 256, 0, stream>>>(att_fc_w, awt_h, awt_l, 768, 512);

  const int nchunks = B_ / NB;
  for (int l = 0; l < L_; ++l) {
    transpose_split<<<dim3(24, 24), 256, 0, stream>>>(q_w + (size_t)l * 768 * 768, wq_h, wq_l, 768, 768);
    transpose_split<<<dim3(48, 24), 256, 0, stream>>>(kv_w + (size_t)l * 768 * 1536, wkv_h, wkv_l, 768, 1536);
    transpose_split<<<dim3(24, 24), 256, 0, stream>>>(proj_w + (size_t)l * 768 * 768, wp_h, wp_l, 768, 768);
    transpose_split<<<dim3(48, 24), 256, 0, stream>>>(fc1_w + (size_t)l * 768 * 1536, wf1_h, wf1_l, 768, 1536);
    transpose_split<<<dim3(24, 48), 256, 0, stream>>>(fc2_w + (size_t)l * 1536 * 768, wf2_h, wf2_l, 1536, 768);
    for (int c = 0; c < nchunks; ++c) {
      const int b0 = c * NB;
      const int Rc = NB * NTOK;
      const int mt = (Rc + 127) / 128;
      float* xc = x_f + (size_t)b0 * NTOK * D_;
      ln_split_kernel<<<Rc, 64, 0, stream>>>(xc, ln1_w + l * D_, ln1_b + l * D_, h_h, h_l);
      gemm_split<0, false, true><<<dim3(mt, 6), 256, 0, stream>>>(
          h_h, h_l, wq_h, wq_l, q_b + l * D_, nullptr, qh, ql, Rc, 768, 768);
      gemm_split<0, false, true><<<dim3(mt, 12), 256, 0, stream>>>(
          h_h, h_l, wkv_h, wkv_l, kv_b + l * 1536, nullptr, kvh, kvl, Rc, 1536, 768);
      attn_mfma<<<dim3(NB, H_, 2), 256, 0, stream>>>(qh, ql, kvh, kvl, h_h, h_l);
      gemm_split<0, true, false><<<dim3(mt, 6), 256, 0, stream>>>(
          h_h, h_l, wp_h, wp_l, proj_b + l * D_, xc, nullptr, nullptr, Rc, 768, 768);
      ln_split_kernel<<<Rc, 64, 0, stream>>>(xc, ln2_w + l * D_, ln2_b + l * D_, h_h, h_l);
      gemm_split<1, false, true><<<dim3(mt, 12), 256, 0, stream>>>(
          h_h, h_l, wf1_h, wf1_l, fc1_b + l * 1536, nullptr, fc1o_h, fc1o_l, Rc, 1536, 768);
      gemm_split<0, true, false><<<dim3(mt, 6), 256, 0, stream>>>(
          fc1o_h, fc1o_l, wf2_h, wf2_l, fc2_b + l * D_, xc, nullptr, nullptr, Rc, 768, 1536);
    }
  }

  gather_split<<<(B_ * K_ * (D_ / 4) + 255) / 256, 256, 0, stream>>>(x_f, lat_h, lat_l);
  gemm_split<2, false, false><<<dim3(16, 4), 256, 0, stream>>>(
      lat_h, lat_l, awt_h, awt_l, att_fc_b, lat, nullptr, nullptr, B_ * K_, TOK_, 768);

  logits_kernel<<<B_ * K_, 64, 0, stream>>>(lat, img_feature_proj, logits);
  select_kernel<<<B_, 64, 0, stream>>>(logits, lat, (float*)d_out,
                                       (float*)d_out + (size_t)B_ * TOPK_ * TOK_);
}

// Round 9
// 2819.807 us; speedup vs baseline: 1.5034x; 1.0725x over previous
//
#include <hip/hip_runtime.h>
#include <math.h>

// Problem constants
#define B_    128
#define P_    197
#define D_    768
#define TOK_  512
#define K_    16
#define TOPK_ 8
#define L_    2
#define H_    12
#define HD_   64
#define NTOK  213            // K_ + P_
#define MROWS (B_ * NTOK)    // 27264
#define QKVN  2304           // fused q|k|v row width

typedef _Float16 f16;
typedef __attribute__((ext_vector_type(8))) _Float16 f16x8;
typedef __attribute__((ext_vector_type(4))) _Float16 f16x4;
typedef __attribute__((ext_vector_type(4))) float f32x4;

__device__ __forceinline__ void gload_lds16(const void* g, void* l) {
  __builtin_amdgcn_global_load_lds(
      (const __attribute__((address_space(1))) unsigned int*)g,
      (__attribute__((address_space(3))) unsigned int*)l, 16, 0, 0);
}

__device__ __forceinline__ float wred_sum(float v) {
#pragma unroll
  for (int o = 32; o > 0; o >>= 1) v += __shfl_xor(v, o);
  return v;
}
__device__ __forceinline__ float wred_max(float v) {
#pragma unroll
  for (int o = 32; o > 0; o >>= 1) v = fmaxf(v, __shfl_xor(v, o));
  return v;
}
__device__ __forceinline__ float red16_max(float v) {
#pragma unroll
  for (int o = 8; o > 0; o >>= 1) v = fmaxf(v, __shfl_xor(v, o));
  return v;
}
__device__ __forceinline__ float red16_sum(float v) {
#pragma unroll
  for (int o = 8; o > 0; o >>= 1) v += __shfl_xor(v, o);
  return v;
}

// ---------------- concat: x = [templates broadcast | img_patch_feats] ----
__global__ __launch_bounds__(256) void concat_kernel(
    const float* __restrict__ tpl, const float* __restrict__ patches,
    float* __restrict__ x) {
  size_t i = (size_t)blockIdx.x * 256 + threadIdx.x;  // one float4 each
  const size_t total = (size_t)MROWS * (D_ / 4);
  if (i >= total) return;
  size_t row = i / (D_ / 4);
  int c = (int)(i % (D_ / 4)) * 4;
  size_t b = row / NTOK;
  int n = (int)(row % NTOK);
  float4 v;
  if (n < K_) v = *(const float4*)(tpl + (size_t)n * D_ + c);
  else        v = *(const float4*)(patches + ((size_t)b * P_ + (n - K_)) * D_ + c);
  *(float4*)(x + row * D_ + c) = v;
}

// ---------------- LayerNorm: one wave per row, f16 hi/lo split out --------
__global__ __launch_bounds__(64) void ln_split_kernel(
    const float* __restrict__ x, const float* __restrict__ w,
    const float* __restrict__ b, f16* __restrict__ yh, f16* __restrict__ yl) {
  size_t row = blockIdx.x;
  int lane = threadIdx.x;
  const float* xr = x + row * D_;
  float4 v[3];
#pragma unroll
  for (int j = 0; j < 3; ++j) v[j] = *(const float4*)(xr + j * 256 + lane * 4);
  float s = 0.f, sq = 0.f;
#pragma unroll
  for (int j = 0; j < 3; ++j) {
    s += v[j].x + v[j].y + v[j].z + v[j].w;
    sq = fmaf(v[j].x, v[j].x, sq); sq = fmaf(v[j].y, v[j].y, sq);
    sq = fmaf(v[j].z, v[j].z, sq); sq = fmaf(v[j].w, v[j].w, sq);
  }
#pragma unroll
  for (int o = 32; o > 0; o >>= 1) { s += __shfl_xor(s, o); sq += __shfl_xor(sq, o); }
  float mean = s * (1.f / D_);
  float var = sq * (1.f / D_) - mean * mean;
  float rs = rsqrtf(var + 1e-5f);
#pragma unroll
  for (int j = 0; j < 3; ++j) {
    int col = j * 256 + lane * 4;
    float4 wv = *(const float4*)(w + col);
    float4 bv = *(const float4*)(b + col);
    float o0 = (v[j].x - mean) * rs * wv.x + bv.x;
    float o1 = (v[j].y - mean) * rs * wv.y + bv.y;
    float o2 = (v[j].z - mean) * rs * wv.z + bv.z;
    float o3 = (v[j].w - mean) * rs * wv.w + bv.w;
    f16x4 hi = {(f16)o0, (f16)o1, (f16)o2, (f16)o3};
    f16x4 lo = {(f16)(o0 - (float)hi[0]), (f16)(o1 - (float)hi[1]),
                (f16)(o2 - (float)hi[2]), (f16)(o3 - (float)hi[3])};
    *(f16x4*)&yh[row * D_ + col] = hi;
    *(f16x4*)&yl[row * D_ + col] = lo;
  }
}

// -------- weight transpose + f16 hi/lo split: W[K][N] -> Wt[N][K] --------
// Wt may be a slice of a larger [Ntot][K] buffer via row offset (host adds).
__global__ __launch_bounds__(256) void transpose_split(
    const float* __restrict__ W, f16* __restrict__ Wh, f16* __restrict__ Wl,
    int Kd, int Nd) {
  __shared__ float t[32][33];
  const int n0 = blockIdx.x * 32, k0 = blockIdx.y * 32;
  const int tx = threadIdx.x & 31, ty = threadIdx.x >> 5;  // 32 x 8
#pragma unroll
  for (int j = 0; j < 4; ++j)
    t[ty + 8 * j][tx] = W[(size_t)(k0 + ty + 8 * j) * Nd + n0 + tx];
  __syncthreads();
#pragma unroll
  for (int j = 0; j < 4; ++j) {
    float v = t[tx][ty + 8 * j];
    f16 hi = (f16)v;
    size_t off = (size_t)(n0 + ty + 8 * j) * Kd + k0 + tx;
    Wh[off] = hi;
    Wl[off] = (f16)(v - (float)hi);
  }
}

// -------- combine q_b (768) and kv_b (1536) into qkv_b (2304) -------------
__global__ __launch_bounds__(256) void combine_bias(
    const float* __restrict__ qb, const float* __restrict__ kvb,
    float* __restrict__ out) {
  int i = blockIdx.x * 256 + threadIdx.x;
  if (i < QKVN) out[i] = (i < D_) ? qb[i] : kvb[i - D_];
}

// ------- split-f16 MFMA GEMM: C = act(A @ Wt^T + bias) [+C] --------------
// Grid: x = N-tiles (inner -> consecutive blocks share the A-tile, L2/L3
// locality), y = M-tiles. 2-phase dbuf, counted vmcnt, chunk swizzle.
template <int ACT, bool RESID, bool OUTSPLIT>
__global__ __launch_bounds__(256) void gemm_split(
    const f16* __restrict__ Ah, const f16* __restrict__ Al,
    const f16* __restrict__ Wh, const f16* __restrict__ Wl,
    const float* __restrict__ bias, float* __restrict__ Cf,
    f16* __restrict__ Ch, f16* __restrict__ Cl, int M, int N, int K) {
  __shared__ __align__(16) f16 S[2][4][128][32];
  const int tid = threadIdx.x;
  const int bn = blockIdx.x * 128, bm = blockIdx.y * 128;
  const int w = tid >> 6, lane = tid & 63;
  const int wm = (w & 1) * 64, wn = (w >> 1) * 64;
  const int fr = lane & 15, kg = lane >> 4;
  f32x4 acc[4][4];
  const f32x4 z = {0.f, 0.f, 0.f, 0.f};
#pragma unroll
  for (int i = 0; i < 4; ++i)
#pragma unroll
    for (int j = 0; j < 4; ++j) acc[i][j] = z;
  const int srow = tid >> 2;
  const int c_l  = (tid & 3) ^ ((tid >> 3) & 3);
  const int cswz = (kg ^ ((fr >> 1) & 3)) * 8;

  auto STAGE = [&](int k0, int buf) {
#pragma unroll
    for (int j = 0; j < 2; ++j) {
      int arow = bm + j * 64 + srow; if (arow >= M) arow = M - 1;
      int brow = bn + j * 64 + srow;
      size_t aoff = (size_t)arow * K + k0 + c_l * 8;
      size_t boff = (size_t)brow * K + k0 + c_l * 8;
      char* base = (char*)&S[buf][0][0][0] + j * 4096 + w * 1024;
      gload_lds16(Ah + aoff, base);
      gload_lds16(Al + aoff, base + 8192);
      gload_lds16(Wh + boff, base + 16384);
      gload_lds16(Wl + boff, base + 24576);
    }
  };
  auto COMPUTE = [&](int buf) {
    f16x8 ah[4], al[4], bh[4], bl[4];
#pragma unroll
    for (int i = 0; i < 4; ++i) {
      ah[i] = *(const f16x8*)&S[buf][0][wm + i * 16 + fr][cswz];
      al[i] = *(const f16x8*)&S[buf][1][wm + i * 16 + fr][cswz];
      bh[i] = *(const f16x8*)&S[buf][2][wn + i * 16 + fr][cswz];
      bl[i] = *(const f16x8*)&S[buf][3][wn + i * 16 + fr][cswz];
    }
#pragma unroll
    for (int i = 0; i < 4; ++i)
#pragma unroll
      for (int j = 0; j < 4; ++j) {
        acc[i][j] = __builtin_amdgcn_mfma_f32_16x16x32_f16(ah[i], bh[j], acc[i][j], 0, 0, 0);
        acc[i][j] = __builtin_amdgcn_mfma_f32_16x16x32_f16(ah[i], bl[j], acc[i][j], 0, 0, 0);
        acc[i][j] = __builtin_amdgcn_mfma_f32_16x16x32_f16(al[i], bh[j], acc[i][j], 0, 0, 0);
      }
  };

  const int nt = K / 32;
  int cur = 0;
  STAGE(0, 0);
  for (int t = 0; t < nt - 1; ++t) {
    STAGE((t + 1) * 32, cur ^ 1);
    asm volatile("s_waitcnt vmcnt(8)" ::: "memory");
    __builtin_amdgcn_s_barrier();
    __builtin_amdgcn_sched_barrier(0);
    COMPUTE(cur);
    __builtin_amdgcn_s_barrier();
    cur ^= 1;
  }
  asm volatile("s_waitcnt vmcnt(0)" ::: "memory");
  __builtin_amdgcn_s_barrier();
  __builtin_amdgcn_sched_barrier(0);
  COMPUTE(cur);

#pragma unroll
  for (int j = 0; j < 4; ++j) {
    const int gc = bn + wn + j * 16 + fr;
    const float bv = bias[gc];
#pragma unroll
    for (int i = 0; i < 4; ++i) {
#pragma unroll
      for (int rg = 0; rg < 4; ++rg) {
        int gr = bm + wm + i * 16 + kg * 4 + rg;
        if (gr < M) {
          float val = acc[i][j][rg] + bv;
          if (ACT == 1) val = fmaxf(val, 0.f);
          if (ACT == 2) val = 1.f / (1.f + expf(-val));
          size_t off = (size_t)gr * N + gc;
          if (OUTSPLIT) {
            f16 hi = (f16)val;
            Ch[off] = hi;
            Cl[off] = (f16)(val - (float)hi);
          } else {
            if (RESID) val += Cf[off];
            Cf[off] = val;
          }
        }
      }
    }
  }
}

// ---------------- MFMA flash attention, split-f16 3-pass ------------------
// Q/K/V read from fused qkv buffer [row][2304]: q +0, k +768, v +1536.
__global__ __launch_bounds__(256) void attn_mfma(
    const f16* __restrict__ QKVh, const f16* __restrict__ QKVl,
    f16* __restrict__ Oh, f16* __restrict__ Ol) {
  __shared__ __align__(16) f16 Ksh[64][64];
  __shared__ __align__(16) f16 Ksl[64][64];
  __shared__ __align__(16) f16 Vsh[64][64];
  __shared__ __align__(16) f16 Vsl[64][64];
  __shared__ __align__(16) f16 Psh[4][32][64];
  __shared__ __align__(16) f16 Psl[4][32][64];
  const int b = blockIdx.x, h = blockIdx.y, zb = blockIdx.z;
  const int tid = threadIdx.x, w = tid >> 6, lane = tid & 63;
  const int fr = lane & 15, kg = lane >> 4;
  const int qbase = zb * 128 + w * 32;
  const size_t rowbase = (size_t)b * NTOK;
  const int hoff = h * HD_;
  const f32x4 z4 = {0.f, 0.f, 0.f, 0.f};

  // Q fragments in registers (persist across K-tiles)
  f16x8 qfh[2][2], qfl[2][2];
#pragma unroll
  for (int mf = 0; mf < 2; ++mf) {
    int qr = qbase + mf * 16 + fr; if (qr >= NTOK) qr = NTOK - 1;
    const size_t ro = (rowbase + qr) * QKVN + hoff;
#pragma unroll
    for (int ks = 0; ks < 2; ++ks) {
      qfh[mf][ks] = *(const f16x8*)&QKVh[ro + ks * 32 + kg * 8];
      qfl[mf][ks] = *(const f16x8*)&QKVl[ro + ks * 32 + kg * 8];
    }
  }

  f32x4 oacc[2][4];
#pragma unroll
  for (int mf = 0; mf < 2; ++mf)
#pragma unroll
    for (int df = 0; df < 4; ++df) oacc[mf][df] = z4;
  float m_r[2][4], l_r[2][4];
#pragma unroll
  for (int mf = 0; mf < 2; ++mf)
#pragma unroll
    for (int rg = 0; rg < 4; ++rg) { m_r[mf][rg] = -INFINITY; l_r[mf][rg] = 0.f; }

  for (int t = 0; t < 4; ++t) {
    const int t0 = t * 64;
    __syncthreads();                      // prior tile fully consumed
    // ---- stage K planes (gload, swizzled source) ----
#pragma unroll
    for (int s = 0; s < 2; ++s) {
      int slot = tid + s * 256;
      int trow = slot >> 3, pch = slot & 7;
      int lch = pch ^ (trow & 7);
      int tok = t0 + trow; if (tok >= NTOK) tok = NTOK - 1;
      size_t src = (rowbase + tok) * (size_t)QKVN + D_ + hoff + lch * 8;
      gload_lds16(QKVh + src, (char*)&Ksh[0][0] + s * 4096 + w * 1024);
      gload_lds16(QKVl + src, (char*)&Ksl[0][0] + s * 4096 + w * 1024);
    }
    // ---- stage V transposed [d][tok], chunk^(d&7) swizzle ----
    {
      int tloc = tid & 63, dg = tid >> 6;
      int tok = t0 + tloc; if (tok >= NTOK) tok = NTOK - 1;
      size_t src = (rowbase + tok) * (size_t)QKVN + 2 * D_ + hoff + dg * 16;
      f16x8 v0h = *(const f16x8*)&QKVh[src];
      f16x8 v1h = *(const f16x8*)&QKVh[src + 8];
      f16x8 v0l = *(const f16x8*)&QKVl[src];
      f16x8 v1l = *(const f16x8*)&QKVl[src + 8];
      int ch = tloc >> 3, pos = tloc & 7;
#pragma unroll
      for (int i = 0; i < 8; ++i) {
        int d0 = dg * 16 + i, d1 = d0 + 8;
        Vsh[d0][((ch ^ (d0 & 7)) << 3) | pos] = v0h[i];
        Vsh[d1][((ch ^ (d1 & 7)) << 3) | pos] = v1h[i];
        Vsl[d0][((ch ^ (d0 & 7)) << 3) | pos] = v0l[i];
        Vsl[d1][((ch ^ (d1 & 7)) << 3) | pos] = v1l[i];
      }
    }
    __syncthreads();                      // staging visible
    // ---- S = QK^T (3-pass split) ----
    f16x8 kbh[4][2], kbl[4][2];
#pragma unroll
    for (int nf = 0; nf < 4; ++nf)
#pragma unroll
      for (int ks = 0; ks < 2; ++ks) {
        int phys = (((ks * 4 + kg) ^ (fr & 7))) * 8;
        kbh[nf][ks] = *(const f16x8*)&Ksh[nf * 16 + fr][phys];
        kbl[nf][ks] = *(const f16x8*)&Ksl[nf * 16 + fr][phys];
      }
    f32x4 sacc[2][4];
#pragma unroll
    for (int mf = 0; mf < 2; ++mf)
#pragma unroll
      for (int nf = 0; nf < 4; ++nf) sacc[mf][nf] = z4;
#pragma unroll
    for (int ks = 0; ks < 2; ++ks)
#pragma unroll
      for (int mf = 0; mf < 2; ++mf)
#pragma unroll
        for (int nf = 0; nf < 4; ++nf) {
          sacc[mf][nf] = __builtin_amdgcn_mfma_f32_16x16x32_f16(qfh[mf][ks], kbh[nf][ks], sacc[mf][nf], 0, 0, 0);
          sacc[mf][nf] = __builtin_amdgcn_mfma_f32_16x16x32_f16(qfh[mf][ks], kbl[nf][ks], sacc[mf][nf], 0, 0, 0);
          sacc[mf][nf] = __builtin_amdgcn_mfma_f32_16x16x32_f16(qfl[mf][ks], kbh[nf][ks], sacc[mf][nf], 0, 0, 0);
        }
    // ---- scale + mask ----
#pragma unroll
    for (int nf = 0; nf < 4; ++nf) {
      bool valid = (t0 + nf * 16 + fr) < NTOK;
#pragma unroll
      for (int mf = 0; mf < 2; ++mf)
#pragma unroll
        for (int rg = 0; rg < 4; ++rg)
          sacc[mf][nf][rg] = valid ? sacc[mf][nf][rg] * 0.125f : -INFINITY;
    }
    // ---- online softmax + P hi/lo -> LDS ----
#pragma unroll
    for (int mf = 0; mf < 2; ++mf) {
      float scl[4];
#pragma unroll
      for (int rg = 0; rg < 4; ++rg) {
        float mx = fmaxf(fmaxf(sacc[mf][0][rg], sacc[mf][1][rg]),
                         fmaxf(sacc[mf][2][rg], sacc[mf][3][rg]));
        mx = red16_max(mx);
        float nm = fmaxf(m_r[mf][rg], mx);
        scl[rg] = __expf(m_r[mf][rg] - nm);
        m_r[mf][rg] = nm;
        float ts = 0.f;
        int qlc = mf * 16 + kg * 4 + rg;
#pragma unroll
        for (int nf = 0; nf < 4; ++nf) {
          float p = __expf(sacc[mf][nf][rg] - nm);
          ts += p;
          f16 ph = (f16)p;
          int tl = nf * 16 + fr;
          int off = (((tl >> 3) ^ (qlc & 7)) << 3) | (tl & 7);
          Psh[w][qlc][off] = ph;
          Psl[w][qlc][off] = (f16)(p - (float)ph);
        }
        ts = red16_sum(ts);
        l_r[mf][rg] = l_r[mf][rg] * scl[rg] + ts;
      }
#pragma unroll
      for (int df = 0; df < 4; ++df)
#pragma unroll
        for (int rg = 0; rg < 4; ++rg)
          oacc[mf][df][rg] *= scl[rg];
    }
    // ---- O += P @ V (3-pass split) ----
    f16x8 vbh[4][2], vbl[4][2];
#pragma unroll
    for (int df = 0; df < 4; ++df)
#pragma unroll
      for (int ks = 0; ks < 2; ++ks) {
        int phys = (((ks * 4 + kg) ^ (fr & 7))) * 8;
        vbh[df][ks] = *(const f16x8*)&Vsh[df * 16 + fr][phys];
        vbl[df][ks] = *(const f16x8*)&Vsl[df * 16 + fr][phys];
      }
    f16x8 pah[2][2], pal[2][2];
#pragma unroll
    for (int mf = 0; mf < 2; ++mf)
#pragma unroll
      for (int ks = 0; ks < 2; ++ks) {
        int phys = (((ks * 4 + kg) ^ (fr & 7))) * 8;
        pah[mf][ks] = *(const f16x8*)&Psh[w][mf * 16 + fr][phys];
        pal[mf][ks] = *(const f16x8*)&Psl[w][mf * 16 + fr][phys];
      }
#pragma unroll
    for (int ks = 0; ks < 2; ++ks)
#pragma unroll
      for (int mf = 0; mf < 2; ++mf)
#pragma unroll
        for (int df = 0; df < 4; ++df) {
          oacc[mf][df] = __builtin_amdgcn_mfma_f32_16x16x32_f16(pah[mf][ks], vbh[df][ks], oacc[mf][df], 0, 0, 0);
          oacc[mf][df] = __builtin_amdgcn_mfma_f32_16x16x32_f16(pah[mf][ks], vbl[df][ks], oacc[mf][df], 0, 0, 0);
          oacc[mf][df] = __builtin_amdgcn_mfma_f32_16x16x32_f16(pal[mf][ks], vbh[df][ks], oacc[mf][df], 0, 0, 0);
        }
  }
  // ---- finalize + store f16 hi/lo ----
#pragma unroll
  for (int mf = 0; mf < 2; ++mf)
#pragma unroll
    for (int rg = 0; rg < 4; ++rg) {
      int qr = qbase + mf * 16 + kg * 4 + rg;
      if (qr < NTOK) {
        float inv = 1.f / l_r[mf][rg];
        size_t ro = (rowbase + qr) * D_ + hoff;
#pragma unroll
        for (int df = 0; df < 4; ++df) {
          float val = oacc[mf][df][rg] * inv;
          f16 hi = (f16)val;
          Oh[ro + df * 16 + fr] = hi;
          Ol[ro + df * 16 + fr] = (f16)(val - (float)hi);
        }
      }
    }
}

// ---------- gather x[:, :16, :] -> f16 hi/lo planes [2048][768] -----------
__global__ __launch_bounds__(256) void gather_split(
    const float* __restrict__ x, f16* __restrict__ oh, f16* __restrict__ ol) {
  int idx = blockIdx.x * 256 + threadIdx.x;
  if (idx >= B_ * K_ * (D_ / 4)) return;
  int row = idx / (D_ / 4);
  int c4 = (idx % (D_ / 4)) * 4;
  int b = row >> 4, k = row & 15;
  const float* src = x + ((size_t)(b * NTOK + k)) * D_ + c4;
  f16x4 hi, lo;
#pragma unroll
  for (int i = 0; i < 4; ++i) {
    float v = src[i];
    hi[i] = (f16)v;
    lo[i] = (f16)(v - (float)hi[i]);
  }
  *(f16x4*)&oh[(size_t)row * D_ + c4] = hi;
  *(f16x4*)&ol[(size_t)row * D_ + c4] = lo;
}

// ---------------- logits[b,k] = dot(lat[b,k,:], proj[b,:]) ----------------
__global__ __launch_bounds__(64) void logits_kernel(
    const float* __restrict__ lat, const float* __restrict__ proj,
    float* __restrict__ logits) {
  int bk = blockIdx.x;
  int b = bk >> 4;
  int lane = threadIdx.x;
  const float* lr = lat + (size_t)bk * TOK_;
  const float* pr = proj + (size_t)b * TOK_;
  float s = 0.f;
#pragma unroll
  for (int i = 0; i < 8; ++i) s = fmaf(lr[lane + 64 * i], pr[lane + 64 * i], s);
  s = wred_sum(s);
  if (lane == 0) logits[bk] = s;
}

// ---------------- softmax + topk select + normalize (1 wave per b) --------
__global__ __launch_bounds__(64) void select_kernel(
    const float* __restrict__ logits, const float* __restrict__ lat,
    float* __restrict__ out_sel, float* __restrict__ out_numr) {
  const int b = blockIdx.x;
  const int lane = threadIdx.x;
  __shared__ float aw_s[16];
  __shared__ int sel_id_s[8];
  __shared__ int numr_s;
  float v = (lane < 16) ? logits[b * 16 + lane] : -INFINITY;
  float mx = wred_max(v);
  float e = (lane < 16) ? expf(v - mx) : 0.f;
  float sum = wred_sum(e);
  float aw = e / sum;
  if (lane < 16) aw_s[lane] = aw;
  unsigned long long ball = __ballot(lane < 16 && aw > 0.05f);
  int counts = __popcll(ball);
  __syncthreads();
  if (lane == 0) {
    int num_r = counts < 1 ? 1 : (counts > TOPK_ ? TOPK_ : counts);
    numr_s = num_r;
    bool used[16];
#pragma unroll
    for (int i = 0; i < 16; ++i) used[i] = false;
    int sorted_idx[8];
    for (int j = 0; j < 8; ++j) {   // descending top-8 (ties: lowest index)
      float bv = -INFINITY; int bi = 0;
      for (int i = 0; i < 16; ++i)
        if (!used[i] && aw_s[i] > bv) { bv = aw_s[i]; bi = i; }
      used[bi] = true;
      sorted_idx[j] = bi;
    }
    int keys[8];
    for (int j = 0; j < 8; ++j) keys[j] = (j < num_r) ? sorted_idx[j] : (16 + j);
    bool kused[8];
    for (int j = 0; j < 8; ++j) kused[j] = false;
    for (int slot = 0; slot < 8; ++slot) {  // perm = argsort(keys), gather
      int bk = 1 << 30, bj = 0;
      for (int j = 0; j < 8; ++j)
        if (!kused[j] && keys[j] < bk) { bk = keys[j]; bj = j; }
      kused[bj] = true;
      sel_id_s[slot] = sorted_idx[bj];
    }
  }
  __syncthreads();
  for (int j = 0; j < 8; ++j) {
    int id = sel_id_s[j];
    const float* row = lat + ((size_t)b * 16 + id) * TOK_;
    float vals[8];
    float sq = 0.f;
#pragma unroll
    for (int i = 0; i < 8; ++i) {
      vals[i] = row[lane + 64 * i];
      sq = fmaf(vals[i], vals[i], sq);
    }
    sq = wred_sum(sq);
    float inv = 1.f / fmaxf(sqrtf(sq), 1e-12f);
#pragma unroll
    for (int i = 0; i < 8; ++i)
      out_sel[((size_t)b * 8 + j) * TOK_ + lane + 64 * i] = vals[i] * inv;
  }
  if (lane == 0) out_numr[b] = (float)numr_s;
}

// ---------------- host launcher -------------------------------------------
extern "C" void kernel_launch(void* const* d_in, const int* in_sizes, int n_in,
                              void* d_out, int out_size, void* d_ws, size_t ws_size,
                              hipStream_t stream) {
  const float* img_feature_proj = (const float*)d_in[0];
  const float* img_patch_feats  = (const float*)d_in[1];
  const float* templates        = (const float*)d_in[2];
  const float* ln1_w  = (const float*)d_in[3];
  const float* ln1_b  = (const float*)d_in[4];
  const float* q_w    = (const float*)d_in[5];
  const float* q_b    = (const float*)d_in[6];
  const float* kv_w   = (const float*)d_in[7];
  const float* kv_b   = (const float*)d_in[8];
  const float* proj_w = (const float*)d_in[9];
  const float* proj_b = (const float*)d_in[10];
  const float* ln2_w  = (const float*)d_in[11];
  const float* ln2_b  = (const float*)d_in[12];
  const float* fc1_w  = (const float*)d_in[13];
  const float* fc1_b  = (const float*)d_in[14];
  const float* fc2_w  = (const float*)d_in[15];
  const float* fc2_b  = (const float*)d_in[16];
  const float* att_fc_w = (const float*)d_in[17];
  const float* att_fc_b = (const float*)d_in[18];

  // ---- fixed workspace ----
  char* ws = (char*)d_ws;
  const size_t XB = (size_t)MROWS * D_ * 4;              // 83,755,008 B
  float* x_f = (float*)ws;  ws += XB;                    // residual fp32
  auto alloc_f16 = [&](size_t n) { f16* p = (f16*)ws; ws += n * 2; return p; };
  // fused qkv weight: [2304][768] hi/lo (q rows 0..767, kv rows 768..2303)
  f16* wqkv_h = alloc_f16((size_t)QKVN * 768);
  f16* wqkv_l = alloc_f16((size_t)QKVN * 768);
  f16* wp_h   = alloc_f16((size_t)768 * 768);
  f16* wp_l   = alloc_f16((size_t)768 * 768);
  f16* wf1_h  = alloc_f16((size_t)1536 * 768);
  f16* wf1_l  = alloc_f16((size_t)1536 * 768);
  f16* wf2_h  = alloc_f16((size_t)768 * 1536);
  f16* wf2_l  = alloc_f16((size_t)768 * 1536);
  f16* awt_h  = alloc_f16((size_t)512 * 768);
  f16* awt_l  = alloc_f16((size_t)512 * 768);
  f16* lat_h  = alloc_f16((size_t)2048 * 768);
  f16* lat_l  = alloc_f16((size_t)2048 * 768);
  float* qkv_b  = (float*)ws; ws += QKVN * 4;
  float* lat    = (float*)ws; ws += (size_t)2048 * 512 * 4;
  float* logits = (float*)ws; ws += 8192;
  const size_t fixed_bytes = (size_t)(ws - (char*)d_ws);

  // ---- adaptive batch-chunk: h planes 4B + qkv planes 12B per elem-row ----
  int NB = B_;
  while (NB > 1) {
    size_t CHE = (size_t)NB * NTOK * D_;
    if (fixed_bytes + 16 * CHE <= ws_size) break;
    NB >>= 1;
  }
  const size_t CHE = (size_t)NB * NTOK * D_;
  f16* h_h   = (f16*)ws;                 // CHE
  f16* h_l   = h_h + CHE;                // CHE
  f16* qkvh  = h_l + CHE;                // 3*CHE
  f16* qkvl  = qkvh + 3 * CHE;           // 3*CHE
  f16* fc1o_h = qkvh;                    // alias: 2*CHE (fits in 3*CHE)
  f16* fc1o_l = qkvl;                    // alias: 2*CHE

  // ---- concat ----
  {
    size_t total = (size_t)MROWS * (D_ / 4);
    concat_kernel<<<(unsigned)((total + 255) / 256), 256, 0, stream>>>(
        templates, img_patch_feats, x_f);
  }
  transpose_split<<<dim3(16, 24), 256, 0, stream>>>(att_fc_w, awt_h, awt_l, 768, 512);

  const int nchunks = B_ / NB;
  for (int l = 0; l < L_; ++l) {
    // fused qkv weight slices
    transpose_split<<<dim3(24, 24), 256, 0, stream>>>(q_w + (size_t)l * 768 * 768, wqkv_h, wqkv_l, 768, 768);
    transpose_split<<<dim3(48, 24), 256, 0, stream>>>(kv_w + (size_t)l * 768 * 1536,
        wqkv_h + (size_t)768 * 768, wqkv_l + (size_t)768 * 768, 768, 1536);
    combine_bias<<<(QKVN + 255) / 256, 256, 0, stream>>>(q_b + l * D_, kv_b + l * 1536, qkv_b);
    transpose_split<<<dim3(24, 24), 256, 0, stream>>>(proj_w + (size_t)l * 768 * 768, wp_h, wp_l, 768, 768);
    transpose_split<<<dim3(48, 24), 256, 0, stream>>>(fc1_w + (size_t)l * 768 * 1536, wf1_h, wf1_l, 768, 1536);
    transpose_split<<<dim3(24, 48), 256, 0, stream>>>(fc2_w + (size_t)l * 1536 * 768, wf2_h, wf2_l, 1536, 768);
    for (int c = 0; c < nchunks; ++c) {
      const int b0 = c * NB;
      const int Rc = NB * NTOK;
      const int mt = (Rc + 127) / 128;
      float* xc = x_f + (size_t)b0 * NTOK * D_;
      ln_split_kernel<<<Rc, 64, 0, stream>>>(xc, ln1_w + l * D_, ln1_b + l * D_, h_h, h_l);
      gemm_split<0, false, true><<<dim3(QKVN / 128, mt), 256, 0, stream>>>(
          h_h, h_l, wqkv_h, wqkv_l, qkv_b, nullptr, qkvh, qkvl, Rc, QKVN, 768);
      attn_mfma<<<dim3(NB, H_, 2), 256, 0, stream>>>(qkvh, qkvl, h_h, h_l);
      gemm_split<0, true, false><<<dim3(6, mt), 256, 0, stream>>>(
          h_h, h_l, wp_h, wp_l, proj_b + l * D_, xc, nullptr, nullptr, Rc, 768, 768);
      ln_split_kernel<<<Rc, 64, 0, stream>>>(xc, ln2_w + l * D_, ln2_b + l * D_, h_h, h_l);
      gemm_split<1, false, true><<<dim3(12, mt), 256, 0, stream>>>(
          h_h, h_l, wf1_h, wf1_l, fc1_b + l * 1536, nullptr, fc1o_h, fc1o_l, Rc, 1536, 768);
      gemm_split<0, true, false><<<dim3(6, mt), 256, 0, stream>>>(
          fc1o_h, fc1o_l, wf2_h, wf2_l, fc2_b + l * D_, xc, nullptr, nullptr, Rc, 768, 1536);
    }
  }

  gather_split<<<(B_ * K_ * (D_ / 4) + 255) / 256, 256, 0, stream>>>(x_f, lat_h, lat_l);
  gemm_split<2, false, false><<<dim3(4, 16), 256, 0, stream>>>(
      lat_h, lat_l, awt_h, awt_l, att_fc_b, lat, nullptr, nullptr, B_ * K_, TOK_, 768);

  logits_kernel<<<B_ * K_, 64, 0, stream>>>(lat, img_feature_proj, logits);
  select_kernel<<<B_, 64, 0, stream>>>(logits, lat, (float*)d_out,
                                       (float*)d_out + (size_t)B_ * TOPK_ * TOK_);
}

// Round 10
// 2735.908 us; speedup vs baseline: 1.5495x; 1.0307x over previous
//
#include <hip/hip_runtime.h>
#include <math.h>

// Problem constants
#define B_    128
#define P_    197
#define D_    768
#define TOK_  512
#define K_    16
#define TOPK_ 8
#define L_    2
#define H_    12
#define HD_   64
#define NTOK  213            // K_ + P_
#define MROWS (B_ * NTOK)    // 27264
#define QKVN  2304           // fused q|k|v row width

typedef _Float16 f16;
typedef __attribute__((ext_vector_type(8))) _Float16 f16x8;
typedef __attribute__((ext_vector_type(4))) _Float16 f16x4;
typedef __attribute__((ext_vector_type(4))) float f32x4;

__device__ __forceinline__ void gload_lds16(const void* g, void* l) {
  __builtin_amdgcn_global_load_lds(
      (const __attribute__((address_space(1))) unsigned int*)g,
      (__attribute__((address_space(3))) unsigned int*)l, 16, 0, 0);
}

__device__ __forceinline__ float wred_sum(float v) {
#pragma unroll
  for (int o = 32; o > 0; o >>= 1) v += __shfl_xor(v, o);
  return v;
}
__device__ __forceinline__ float wred_max(float v) {
#pragma unroll
  for (int o = 32; o > 0; o >>= 1) v = fmaxf(v, __shfl_xor(v, o));
  return v;
}
__device__ __forceinline__ float red16_max(float v) {
#pragma unroll
  for (int o = 8; o > 0; o >>= 1) v = fmaxf(v, __shfl_xor(v, o));
  return v;
}
__device__ __forceinline__ float red16_sum(float v) {
#pragma unroll
  for (int o = 8; o > 0; o >>= 1) v += __shfl_xor(v, o);
  return v;
}

// ---------------- concat: x = [templates broadcast | img_patch_feats] ----
__global__ __launch_bounds__(256) void concat_kernel(
    const float* __restrict__ tpl, const float* __restrict__ patches,
    float* __restrict__ x) {
  size_t i = (size_t)blockIdx.x * 256 + threadIdx.x;  // one float4 each
  const size_t total = (size_t)MROWS * (D_ / 4);
  if (i >= total) return;
  size_t row = i / (D_ / 4);
  int c = (int)(i % (D_ / 4)) * 4;
  size_t b = row / NTOK;
  int n = (int)(row % NTOK);
  float4 v;
  if (n < K_) v = *(const float4*)(tpl + (size_t)n * D_ + c);
  else        v = *(const float4*)(patches + ((size_t)b * P_ + (n - K_)) * D_ + c);
  *(float4*)(x + row * D_ + c) = v;
}

// ---------------- LayerNorm: one wave per row, f16 hi/lo split out --------
__global__ __launch_bounds__(64) void ln_split_kernel(
    const float* __restrict__ x, const float* __restrict__ w,
    const float* __restrict__ b, f16* __restrict__ yh, f16* __restrict__ yl) {
  size_t row = blockIdx.x;
  int lane = threadIdx.x;
  const float* xr = x + row * D_;
  float4 v[3];
#pragma unroll
  for (int j = 0; j < 3; ++j) v[j] = *(const float4*)(xr + j * 256 + lane * 4);
  float s = 0.f, sq = 0.f;
#pragma unroll
  for (int j = 0; j < 3; ++j) {
    s += v[j].x + v[j].y + v[j].z + v[j].w;
    sq = fmaf(v[j].x, v[j].x, sq); sq = fmaf(v[j].y, v[j].y, sq);
    sq = fmaf(v[j].z, v[j].z, sq); sq = fmaf(v[j].w, v[j].w, sq);
  }
#pragma unroll
  for (int o = 32; o > 0; o >>= 1) { s += __shfl_xor(s, o); sq += __shfl_xor(sq, o); }
  float mean = s * (1.f / D_);
  float var = sq * (1.f / D_) - mean * mean;
  float rs = rsqrtf(var + 1e-5f);
#pragma unroll
  for (int j = 0; j < 3; ++j) {
    int col = j * 256 + lane * 4;
    float4 wv = *(const float4*)(w + col);
    float4 bv = *(const float4*)(b + col);
    float o0 = (v[j].x - mean) * rs * wv.x + bv.x;
    float o1 = (v[j].y - mean) * rs * wv.y + bv.y;
    float o2 = (v[j].z - mean) * rs * wv.z + bv.z;
    float o3 = (v[j].w - mean) * rs * wv.w + bv.w;
    f16x4 hi = {(f16)o0, (f16)o1, (f16)o2, (f16)o3};
    f16x4 lo = {(f16)(o0 - (float)hi[0]), (f16)(o1 - (float)hi[1]),
                (f16)(o2 - (float)hi[2]), (f16)(o3 - (float)hi[3])};
    *(f16x4*)&yh[row * D_ + col] = hi;
    *(f16x4*)&yl[row * D_ + col] = lo;
  }
}

// -------- weight transpose + f16 hi/lo split: W[K][N] -> Wt[N][K] --------
__global__ __launch_bounds__(256) void transpose_split(
    const float* __restrict__ W, f16* __restrict__ Wh, f16* __restrict__ Wl,
    int Kd, int Nd) {
  __shared__ float t[32][33];
  const int n0 = blockIdx.x * 32, k0 = blockIdx.y * 32;
  const int tx = threadIdx.x & 31, ty = threadIdx.x >> 5;  // 32 x 8
#pragma unroll
  for (int j = 0; j < 4; ++j)
    t[ty + 8 * j][tx] = W[(size_t)(k0 + ty + 8 * j) * Nd + n0 + tx];
  __syncthreads();
#pragma unroll
  for (int j = 0; j < 4; ++j) {
    float v = t[tx][ty + 8 * j];
    f16 hi = (f16)v;
    size_t off = (size_t)(n0 + ty + 8 * j) * Kd + k0 + tx;
    Wh[off] = hi;
    Wl[off] = (f16)(v - (float)hi);
  }
}

// -------- combine q_b (768) and kv_b (1536) into qkv_b (2304) -------------
__global__ __launch_bounds__(256) void combine_bias(
    const float* __restrict__ qb, const float* __restrict__ kvb,
    float* __restrict__ out) {
  int i = blockIdx.x * 256 + threadIdx.x;
  if (i < QKVN) out[i] = (i < D_) ? qb[i] : kvb[i - D_];
}

// ------- split-f16 MFMA GEMM: C = act(A @ Wt^T + bias) [+C] --------------
// 1D grid with bijective XCD-chunked swizzle (T1/m204): each XCD owns a
// contiguous run of work-items ordered N-inner, so an A-tile is walked
// across all N-tiles from ONE XCD's L2 (fetched from HBM once).
// 2-phase dbuf, counted vmcnt, chunk swizzle (unchanged).
template <int ACT, bool RESID, bool OUTSPLIT>
__global__ __launch_bounds__(256) void gemm_split(
    const f16* __restrict__ Ah, const f16* __restrict__ Al,
    const f16* __restrict__ Wh, const f16* __restrict__ Wl,
    const float* __restrict__ bias, float* __restrict__ Cf,
    f16* __restrict__ Ch, f16* __restrict__ Cl, int M, int N, int K) {
  __shared__ __align__(16) f16 S[2][4][128][32];
  const int tid = threadIdx.x;
  // --- XCD-aware bijective remap (8 XCDs, round-robin dispatch) ---
  const int nwg = gridDim.x;
  const int bid = blockIdx.x;
  const int xcd = bid & 7, idx = bid >> 3;
  const int qc = nwg >> 3, rc = nwg & 7;
  const int o = (xcd < rc ? xcd * (qc + 1) : rc * (qc + 1) + (xcd - rc) * qc) + idx;
  const int ntx = N >> 7;
  const int bn = (o % ntx) * 128, bm = (o / ntx) * 128;

  const int w = tid >> 6, lane = tid & 63;
  const int wm = (w & 1) * 64, wn = (w >> 1) * 64;
  const int fr = lane & 15, kg = lane >> 4;
  f32x4 acc[4][4];
  const f32x4 z = {0.f, 0.f, 0.f, 0.f};
#pragma unroll
  for (int i = 0; i < 4; ++i)
#pragma unroll
    for (int j = 0; j < 4; ++j) acc[i][j] = z;
  const int srow = tid >> 2;
  const int c_l  = (tid & 3) ^ ((tid >> 3) & 3);
  const int cswz = (kg ^ ((fr >> 1) & 3)) * 8;

  auto STAGE = [&](int k0, int buf) {
#pragma unroll
    for (int j = 0; j < 2; ++j) {
      int arow = bm + j * 64 + srow; if (arow >= M) arow = M - 1;
      int brow = bn + j * 64 + srow;
      size_t aoff = (size_t)arow * K + k0 + c_l * 8;
      size_t boff = (size_t)brow * K + k0 + c_l * 8;
      char* base = (char*)&S[buf][0][0][0] + j * 4096 + w * 1024;
      gload_lds16(Ah + aoff, base);
      gload_lds16(Al + aoff, base + 8192);
      gload_lds16(Wh + boff, base + 16384);
      gload_lds16(Wl + boff, base + 24576);
    }
  };
  auto COMPUTE = [&](int buf) {
    f16x8 ah[4], al[4], bh[4], bl[4];
#pragma unroll
    for (int i = 0; i < 4; ++i) {
      ah[i] = *(const f16x8*)&S[buf][0][wm + i * 16 + fr][cswz];
      al[i] = *(const f16x8*)&S[buf][1][wm + i * 16 + fr][cswz];
      bh[i] = *(const f16x8*)&S[buf][2][wn + i * 16 + fr][cswz];
      bl[i] = *(const f16x8*)&S[buf][3][wn + i * 16 + fr][cswz];
    }
#pragma unroll
    for (int i = 0; i < 4; ++i)
#pragma unroll
      for (int j = 0; j < 4; ++j) {
        acc[i][j] = __builtin_amdgcn_mfma_f32_16x16x32_f16(ah[i], bh[j], acc[i][j], 0, 0, 0);
        acc[i][j] = __builtin_amdgcn_mfma_f32_16x16x32_f16(ah[i], bl[j], acc[i][j], 0, 0, 0);
        acc[i][j] = __builtin_amdgcn_mfma_f32_16x16x32_f16(al[i], bh[j], acc[i][j], 0, 0, 0);
      }
  };

  const int nt = K / 32;
  int cur = 0;
  STAGE(0, 0);
  for (int t = 0; t < nt - 1; ++t) {
    STAGE((t + 1) * 32, cur ^ 1);
    asm volatile("s_waitcnt vmcnt(8)" ::: "memory");
    __builtin_amdgcn_s_barrier();
    __builtin_amdgcn_sched_barrier(0);
    COMPUTE(cur);
    __builtin_amdgcn_s_barrier();
    cur ^= 1;
  }
  asm volatile("s_waitcnt vmcnt(0)" ::: "memory");
  __builtin_amdgcn_s_barrier();
  __builtin_amdgcn_sched_barrier(0);
  COMPUTE(cur);

#pragma unroll
  for (int j = 0; j < 4; ++j) {
    const int gc = bn + wn + j * 16 + fr;
    const float bv = bias[gc];
#pragma unroll
    for (int i = 0; i < 4; ++i) {
#pragma unroll
      for (int rg = 0; rg < 4; ++rg) {
        int gr = bm + wm + i * 16 + kg * 4 + rg;
        if (gr < M) {
          float val = acc[i][j][rg] + bv;
          if (ACT == 1) val = fmaxf(val, 0.f);
          if (ACT == 2) val = 1.f / (1.f + expf(-val));
          size_t off = (size_t)gr * N + gc;
          if (OUTSPLIT) {
            f16 hi = (f16)val;
            Ch[off] = hi;
            Cl[off] = (f16)(val - (float)hi);
          } else {
            if (RESID) val += Cf[off];
            Cf[off] = val;
          }
        }
      }
    }
  }
}

// ---------------- MFMA flash attention, split-f16 3-pass ------------------
// Q/K/V read from fused qkv buffer [row][2304]: q +0, k +768, v +1536.
__global__ __launch_bounds__(256) void attn_mfma(
    const f16* __restrict__ QKVh, const f16* __restrict__ QKVl,
    f16* __restrict__ Oh, f16* __restrict__ Ol) {
  __shared__ __align__(16) f16 Ksh[64][64];
  __shared__ __align__(16) f16 Ksl[64][64];
  __shared__ __align__(16) f16 Vsh[64][64];
  __shared__ __align__(16) f16 Vsl[64][64];
  __shared__ __align__(16) f16 Psh[4][32][64];
  __shared__ __align__(16) f16 Psl[4][32][64];
  const int b = blockIdx.x, h = blockIdx.y, zb = blockIdx.z;
  const int tid = threadIdx.x, w = tid >> 6, lane = tid & 63;
  const int fr = lane & 15, kg = lane >> 4;
  const int qbase = zb * 128 + w * 32;
  const size_t rowbase = (size_t)b * NTOK;
  const int hoff = h * HD_;
  const f32x4 z4 = {0.f, 0.f, 0.f, 0.f};

  f16x8 qfh[2][2], qfl[2][2];
#pragma unroll
  for (int mf = 0; mf < 2; ++mf) {
    int qr = qbase + mf * 16 + fr; if (qr >= NTOK) qr = NTOK - 1;
    const size_t ro = (rowbase + qr) * QKVN + hoff;
#pragma unroll
    for (int ks = 0; ks < 2; ++ks) {
      qfh[mf][ks] = *(const f16x8*)&QKVh[ro + ks * 32 + kg * 8];
      qfl[mf][ks] = *(const f16x8*)&QKVl[ro + ks * 32 + kg * 8];
    }
  }

  f32x4 oacc[2][4];
#pragma unroll
  for (int mf = 0; mf < 2; ++mf)
#pragma unroll
    for (int df = 0; df < 4; ++df) oacc[mf][df] = z4;
  float m_r[2][4], l_r[2][4];
#pragma unroll
  for (int mf = 0; mf < 2; ++mf)
#pragma unroll
    for (int rg = 0; rg < 4; ++rg) { m_r[mf][rg] = -INFINITY; l_r[mf][rg] = 0.f; }

  for (int t = 0; t < 4; ++t) {
    const int t0 = t * 64;
    __syncthreads();
#pragma unroll
    for (int s = 0; s < 2; ++s) {
      int slot = tid + s * 256;
      int trow = slot >> 3, pch = slot & 7;
      int lch = pch ^ (trow & 7);
      int tok = t0 + trow; if (tok >= NTOK) tok = NTOK - 1;
      size_t src = (rowbase + tok) * (size_t)QKVN + D_ + hoff + lch * 8;
      gload_lds16(QKVh + src, (char*)&Ksh[0][0] + s * 4096 + w * 1024);
      gload_lds16(QKVl + src, (char*)&Ksl[0][0] + s * 4096 + w * 1024);
    }
    {
      int tloc = tid & 63, dg = tid >> 6;
      int tok = t0 + tloc; if (tok >= NTOK) tok = NTOK - 1;
      size_t src = (rowbase + tok) * (size_t)QKVN + 2 * D_ + hoff + dg * 16;
      f16x8 v0h = *(const f16x8*)&QKVh[src];
      f16x8 v1h = *(const f16x8*)&QKVh[src + 8];
      f16x8 v0l = *(const f16x8*)&QKVl[src];
      f16x8 v1l = *(const f16x8*)&QKVl[src + 8];
      int ch = tloc >> 3, pos = tloc & 7;
#pragma unroll
      for (int i = 0; i < 8; ++i) {
        int d0 = dg * 16 + i, d1 = d0 + 8;
        Vsh[d0][((ch ^ (d0 & 7)) << 3) | pos] = v0h[i];
        Vsh[d1][((ch ^ (d1 & 7)) << 3) | pos] = v1h[i];
        Vsl[d0][((ch ^ (d0 & 7)) << 3) | pos] = v0l[i];
        Vsl[d1][((ch ^ (d1 & 7)) << 3) | pos] = v1l[i];
      }
    }
    __syncthreads();
    f16x8 kbh[4][2], kbl[4][2];
#pragma unroll
    for (int nf = 0; nf < 4; ++nf)
#pragma unroll
      for (int ks = 0; ks < 2; ++ks) {
        int phys = (((ks * 4 + kg) ^ (fr & 7))) * 8;
        kbh[nf][ks] = *(const f16x8*)&Ksh[nf * 16 + fr][phys];
        kbl[nf][ks] = *(const f16x8*)&Ksl[nf * 16 + fr][phys];
      }
    f32x4 sacc[2][4];
#pragma unroll
    for (int mf = 0; mf < 2; ++mf)
#pragma unroll
      for (int nf = 0; nf < 4; ++nf) sacc[mf][nf] = z4;
#pragma unroll
    for (int ks = 0; ks < 2; ++ks)
#pragma unroll
      for (int mf = 0; mf < 2; ++mf)
#pragma unroll
        for (int nf = 0; nf < 4; ++nf) {
          sacc[mf][nf] = __builtin_amdgcn_mfma_f32_16x16x32_f16(qfh[mf][ks], kbh[nf][ks], sacc[mf][nf], 0, 0, 0);
          sacc[mf][nf] = __builtin_amdgcn_mfma_f32_16x16x32_f16(qfh[mf][ks], kbl[nf][ks], sacc[mf][nf], 0, 0, 0);
          sacc[mf][nf] = __builtin_amdgcn_mfma_f32_16x16x32_f16(qfl[mf][ks], kbh[nf][ks], sacc[mf][nf], 0, 0, 0);
        }
#pragma unroll
    for (int nf = 0; nf < 4; ++nf) {
      bool valid = (t0 + nf * 16 + fr) < NTOK;
#pragma unroll
      for (int mf = 0; mf < 2; ++mf)
#pragma unroll
        for (int rg = 0; rg < 4; ++rg)
          sacc[mf][nf][rg] = valid ? sacc[mf][nf][rg] * 0.125f : -INFINITY;
    }
#pragma unroll
    for (int mf = 0; mf < 2; ++mf) {
      float scl[4];
#pragma unroll
      for (int rg = 0; rg < 4; ++rg) {
        float mx = fmaxf(fmaxf(sacc[mf][0][rg], sacc[mf][1][rg]),
                         fmaxf(sacc[mf][2][rg], sacc[mf][3][rg]));
        mx = red16_max(mx);
        float nm = fmaxf(m_r[mf][rg], mx);
        scl[rg] = __expf(m_r[mf][rg] - nm);
        m_r[mf][rg] = nm;
        float ts = 0.f;
        int qlc = mf * 16 + kg * 4 + rg;
#pragma unroll
        for (int nf = 0; nf < 4; ++nf) {
          float p = __expf(sacc[mf][nf][rg] - nm);
          ts += p;
          f16 ph = (f16)p;
          int tl = nf * 16 + fr;
          int off = (((tl >> 3) ^ (qlc & 7)) << 3) | (tl & 7);
          Psh[w][qlc][off] = ph;
          Psl[w][qlc][off] = (f16)(p - (float)ph);
        }
        ts = red16_sum(ts);
        l_r[mf][rg] = l_r[mf][rg] * scl[rg] + ts;
      }
#pragma unroll
      for (int df = 0; df < 4; ++df)
#pragma unroll
        for (int rg = 0; rg < 4; ++rg)
          oacc[mf][df][rg] *= scl[rg];
    }
    f16x8 vbh[4][2], vbl[4][2];
#pragma unroll
    for (int df = 0; df < 4; ++df)
#pragma unroll
      for (int ks = 0; ks < 2; ++ks) {
        int phys = (((ks * 4 + kg) ^ (fr & 7))) * 8;
        vbh[df][ks] = *(const f16x8*)&Vsh[df * 16 + fr][phys];
        vbl[df][ks] = *(const f16x8*)&Vsl[df * 16 + fr][phys];
      }
    f16x8 pah[2][2], pal[2][2];
#pragma unroll
    for (int mf = 0; mf < 2; ++mf)
#pragma unroll
      for (int ks = 0; ks < 2; ++ks) {
        int phys = (((ks * 4 + kg) ^ (fr & 7))) * 8;
        pah[mf][ks] = *(const f16x8*)&Psh[w][mf * 16 + fr][phys];
        pal[mf][ks] = *(const f16x8*)&Psl[w][mf * 16 + fr][phys];
      }
#pragma unroll
    for (int ks = 0; ks < 2; ++ks)
#pragma unroll
      for (int mf = 0; mf < 2; ++mf)
#pragma unroll
        for (int df = 0; df < 4; ++df) {
          oacc[mf][df] = __builtin_amdgcn_mfma_f32_16x16x32_f16(pah[mf][ks], vbh[df][ks], oacc[mf][df], 0, 0, 0);
          oacc[mf][df] = __builtin_amdgcn_mfma_f32_16x16x32_f16(pah[mf][ks], vbl[df][ks], oacc[mf][df], 0, 0, 0);
          oacc[mf][df] = __builtin_amdgcn_mfma_f32_16x16x32_f16(pal[mf][ks], vbh[df][ks], oacc[mf][df], 0, 0, 0);
        }
  }
#pragma unroll
  for (int mf = 0; mf < 2; ++mf)
#pragma unroll
    for (int rg = 0; rg < 4; ++rg) {
      int qr = qbase + mf * 16 + kg * 4 + rg;
      if (qr < NTOK) {
        float inv = 1.f / l_r[mf][rg];
        size_t ro = (rowbase + qr) * D_ + hoff;
#pragma unroll
        for (int df = 0; df < 4; ++df) {
          float val = oacc[mf][df][rg] * inv;
          f16 hi = (f16)val;
          Oh[ro + df * 16 + fr] = hi;
          Ol[ro + df * 16 + fr] = (f16)(val - (float)hi);
        }
      }
    }
}

// ---------- gather x[:, :16, :] -> f16 hi/lo planes [2048][768] -----------
__global__ __launch_bounds__(256) void gather_split(
    const float* __restrict__ x, f16* __restrict__ oh, f16* __restrict__ ol) {
  int idx = blockIdx.x * 256 + threadIdx.x;
  if (idx >= B_ * K_ * (D_ / 4)) return;
  int row = idx / (D_ / 4);
  int c4 = (idx % (D_ / 4)) * 4;
  int b = row >> 4, k = row & 15;
  const float* src = x + ((size_t)(b * NTOK + k)) * D_ + c4;
  f16x4 hi, lo;
#pragma unroll
  for (int i = 0; i < 4; ++i) {
    float v = src[i];
    hi[i] = (f16)v;
    lo[i] = (f16)(v - (float)hi[i]);
  }
  *(f16x4*)&oh[(size_t)row * D_ + c4] = hi;
  *(f16x4*)&ol[(size_t)row * D_ + c4] = lo;
}

// ---------------- logits[b,k] = dot(lat[b,k,:], proj[b,:]) ----------------
__global__ __launch_bounds__(64) void logits_kernel(
    const float* __restrict__ lat, const float* __restrict__ proj,
    float* __restrict__ logits) {
  int bk = blockIdx.x;
  int b = bk >> 4;
  int lane = threadIdx.x;
  const float* lr = lat + (size_t)bk * TOK_;
  const float* pr = proj + (size_t)b * TOK_;
  float s = 0.f;
#pragma unroll
  for (int i = 0; i < 8; ++i) s = fmaf(lr[lane + 64 * i], pr[lane + 64 * i], s);
  s = wred_sum(s);
  if (lane == 0) logits[bk] = s;
}

// ---------------- softmax + topk select + normalize (1 wave per b) --------
__global__ __launch_bounds__(64) void select_kernel(
    const float* __restrict__ logits, const float* __restrict__ lat,
    float* __restrict__ out_sel, float* __restrict__ out_numr) {
  const int b = blockIdx.x;
  const int lane = threadIdx.x;
  __shared__ float aw_s[16];
  __shared__ int sel_id_s[8];
  __shared__ int numr_s;
  float v = (lane < 16) ? logits[b * 16 + lane] : -INFINITY;
  float mx = wred_max(v);
  float e = (lane < 16) ? expf(v - mx) : 0.f;
  float sum = wred_sum(e);
  float aw = e / sum;
  if (lane < 16) aw_s[lane] = aw;
  unsigned long long ball = __ballot(lane < 16 && aw > 0.05f);
  int counts = __popcll(ball);
  __syncthreads();
  if (lane == 0) {
    int num_r = counts < 1 ? 1 : (counts > TOPK_ ? TOPK_ : counts);
    numr_s = num_r;
    bool used[16];
#pragma unroll
    for (int i = 0; i < 16; ++i) used[i] = false;
    int sorted_idx[8];
    for (int j = 0; j < 8; ++j) {   // descending top-8 (ties: lowest index)
      float bv = -INFINITY; int bi = 0;
      for (int i = 0; i < 16; ++i)
        if (!used[i] && aw_s[i] > bv) { bv = aw_s[i]; bi = i; }
      used[bi] = true;
      sorted_idx[j] = bi;
    }
    int keys[8];
    for (int j = 0; j < 8; ++j) keys[j] = (j < num_r) ? sorted_idx[j] : (16 + j);
    bool kused[8];
    for (int j = 0; j < 8; ++j) kused[j] = false;
    for (int slot = 0; slot < 8; ++slot) {  // perm = argsort(keys), gather
      int bk = 1 << 30, bj = 0;
      for (int j = 0; j < 8; ++j)
        if (!kused[j] && keys[j] < bk) { bk = keys[j]; bj = j; }
      kused[bj] = true;
      sel_id_s[slot] = sorted_idx[bj];
    }
  }
  __syncthreads();
  for (int j = 0; j < 8; ++j) {
    int id = sel_id_s[j];
    const float* row = lat + ((size_t)b * 16 + id) * TOK_;
    float vals[8];
    float sq = 0.f;
#pragma unroll
    for (int i = 0; i < 8; ++i) {
      vals[i] = row[lane + 64 * i];
      sq = fmaf(vals[i], vals[i], sq);
    }
    sq = wred_sum(sq);
    float inv = 1.f / fmaxf(sqrtf(sq), 1e-12f);
#pragma unroll
    for (int i = 0; i < 8; ++i)
      out_sel[((size_t)b * 8 + j) * TOK_ + lane + 64 * i] = vals[i] * inv;
  }
  if (lane == 0) out_numr[b] = (float)numr_s;
}

// ---------------- host launcher -------------------------------------------
extern "C" void kernel_launch(void* const* d_in, const int* in_sizes, int n_in,
                              void* d_out, int out_size, void* d_ws, size_t ws_size,
                              hipStream_t stream) {
  const float* img_feature_proj = (const float*)d_in[0];
  const float* img_patch_feats  = (const float*)d_in[1];
  const float* templates        = (const float*)d_in[2];
  const float* ln1_w  = (const float*)d_in[3];
  const float* ln1_b  = (const float*)d_in[4];
  const float* q_w    = (const float*)d_in[5];
  const float* q_b    = (const float*)d_in[6];
  const float* kv_w   = (const float*)d_in[7];
  const float* kv_b   = (const float*)d_in[8];
  const float* proj_w = (const float*)d_in[9];
  const float* proj_b = (const float*)d_in[10];
  const float* ln2_w  = (const float*)d_in[11];
  const float* ln2_b  = (const float*)d_in[12];
  const float* fc1_w  = (const float*)d_in[13];
  const float* fc1_b  = (const float*)d_in[14];
  const float* fc2_w  = (const float*)d_in[15];
  const float* fc2_b  = (const float*)d_in[16];
  const float* att_fc_w = (const float*)d_in[17];
  const float* att_fc_b = (const float*)d_in[18];

  // ---- fixed workspace ----
  char* ws = (char*)d_ws;
  const size_t XB = (size_t)MROWS * D_ * 4;              // 83,755,008 B
  float* x_f = (float*)ws;  ws += XB;                    // residual fp32
  auto alloc_f16 = [&](size_t n) { f16* p = (f16*)ws; ws += n * 2; return p; };
  f16* wqkv_h = alloc_f16((size_t)QKVN * 768);
  f16* wqkv_l = alloc_f16((size_t)QKVN * 768);
  f16* wp_h   = alloc_f16((size_t)768 * 768);
  f16* wp_l   = alloc_f16((size_t)768 * 768);
  f16* wf1_h  = alloc_f16((size_t)1536 * 768);
  f16* wf1_l  = alloc_f16((size_t)1536 * 768);
  f16* wf2_h  = alloc_f16((size_t)768 * 1536);
  f16* wf2_l  = alloc_f16((size_t)768 * 1536);
  f16* awt_h  = alloc_f16((size_t)512 * 768);
  f16* awt_l  = alloc_f16((size_t)512 * 768);
  f16* lat_h  = alloc_f16((size_t)2048 * 768);
  f16* lat_l  = alloc_f16((size_t)2048 * 768);
  float* qkv_b  = (float*)ws; ws += QKVN * 4;
  float* lat    = (float*)ws; ws += (size_t)2048 * 512 * 4;
  float* logits = (float*)ws; ws += 8192;
  const size_t fixed_bytes = (size_t)(ws - (char*)d_ws);

  // ---- adaptive batch-chunk: h planes 4B + qkv planes 12B per elem-row ----
  int NB = B_;
  while (NB > 1) {
    size_t CHE = (size_t)NB * NTOK * D_;
    if (fixed_bytes + 16 * CHE <= ws_size) break;
    NB >>= 1;
  }
  const size_t CHE = (size_t)NB * NTOK * D_;
  f16* h_h   = (f16*)ws;                 // CHE
  f16* h_l   = h_h + CHE;                // CHE
  f16* qkvh  = h_l + CHE;                // 3*CHE
  f16* qkvl  = qkvh + 3 * CHE;           // 3*CHE
  f16* fc1o_h = qkvh;                    // alias: 2*CHE
  f16* fc1o_l = qkvl;                    // alias: 2*CHE

  // ---- concat ----
  {
    size_t total = (size_t)MROWS * (D_ / 4);
    concat_kernel<<<(unsigned)((total + 255) / 256), 256, 0, stream>>>(
        templates, img_patch_feats, x_f);
  }
  transpose_split<<<dim3(16, 24), 256, 0, stream>>>(att_fc_w, awt_h, awt_l, 768, 512);

  const int nchunks = B_ / NB;
  for (int l = 0; l < L_; ++l) {
    transpose_split<<<dim3(24, 24), 256, 0, stream>>>(q_w + (size_t)l * 768 * 768, wqkv_h, wqkv_l, 768, 768);
    transpose_split<<<dim3(48, 24), 256, 0, stream>>>(kv_w + (size_t)l * 768 * 1536,
        wqkv_h + (size_t)768 * 768, wqkv_l + (size_t)768 * 768, 768, 1536);
    combine_bias<<<(QKVN + 255) / 256, 256, 0, stream>>>(q_b + l * D_, kv_b + l * 1536, qkv_b);
    transpose_split<<<dim3(24, 24), 256, 0, stream>>>(proj_w + (size_t)l * 768 * 768, wp_h, wp_l, 768, 768);
    transpose_split<<<dim3(48, 24), 256, 0, stream>>>(fc1_w + (size_t)l * 768 * 1536, wf1_h, wf1_l, 768, 1536);
    transpose_split<<<dim3(24, 48), 256, 0, stream>>>(fc2_w + (size_t)l * 1536 * 768, wf2_h, wf2_l, 1536, 768);
    for (int c = 0; c < nchunks; ++c) {
      const int b0 = c * NB;
      const int Rc = NB * NTOK;
      const int mt = (Rc + 127) / 128;
      float* xc = x_f + (size_t)b0 * NTOK * D_;
      ln_split_kernel<<<Rc, 64, 0, stream>>>(xc, ln1_w + l * D_, ln1_b + l * D_, h_h, h_l);
      gemm_split<0, false, true><<<(QKVN / 128) * mt, 256, 0, stream>>>(
          h_h, h_l, wqkv_h, wqkv_l, qkv_b, nullptr, qkvh, qkvl, Rc, QKVN, 768);
      attn_mfma<<<dim3(NB, H_, 2), 256, 0, stream>>>(qkvh, qkvl, h_h, h_l);
      gemm_split<0, true, false><<<6 * mt, 256, 0, stream>>>(
          h_h, h_l, wp_h, wp_l, proj_b + l * D_, xc, nullptr, nullptr, Rc, 768, 768);
      ln_split_kernel<<<Rc, 64, 0, stream>>>(xc, ln2_w + l * D_, ln2_b + l * D_, h_h, h_l);
      gemm_split<1, false, true><<<12 * mt, 256, 0, stream>>>(
          h_h, h_l, wf1_h, wf1_l, fc1_b + l * 1536, nullptr, fc1o_h, fc1o_l, Rc, 1536, 768);
      gemm_split<0, true, false><<<6 * mt, 256, 0, stream>>>(
          fc1o_h, fc1o_l, wf2_h, wf2_l, fc2_b + l * D_, xc, nullptr, nullptr, Rc, 768, 1536);
    }
  }

  gather_split<<<(B_ * K_ * (D_ / 4) + 255) / 256, 256, 0, stream>>>(x_f, lat_h, lat_l);
  gemm_split<2, false, false><<<4 * 16, 256, 0, stream>>>(
      lat_h, lat_l, awt_h, awt_l, att_fc_b, lat, nullptr, nullptr, B_ * K_, TOK_, 768);

  logits_kernel<<<B_ * K_, 64, 0, stream>>>(lat, img_feature_proj, logits);
  select_kernel<<<B_, 64, 0, stream>>>(logits, lat, (float*)d_out,
                                       (float*)d_out + (size_t)B_ * TOPK_ * TOK_);
}

// Round 11
// 2685.689 us; speedup vs baseline: 1.5785x; 1.0187x over previous
//
#include <hip/hip_runtime.h>
#include <math.h>

// Problem constants
#define B_    128
#define P_    197
#define D_    768
#define TOK_  512
#define K_    16
#define TOPK_ 8
#define L_    2
#define H_    12
#define HD_   64
#define NTOK  213            // K_ + P_
#define MROWS (B_ * NTOK)    // 27264
#define QKVN  2304           // fused q|k|v row width

typedef _Float16 f16;
typedef __attribute__((ext_vector_type(8))) _Float16 f16x8;
typedef __attribute__((ext_vector_type(4))) _Float16 f16x4;
typedef __attribute__((ext_vector_type(4))) float f32x4;

__device__ __forceinline__ void gload_lds16(const void* g, void* l) {
  __builtin_amdgcn_global_load_lds(
      (const __attribute__((address_space(1))) unsigned int*)g,
      (__attribute__((address_space(3))) unsigned int*)l, 16, 0, 0);
}

__device__ __forceinline__ float wred_sum(float v) {
#pragma unroll
  for (int o = 32; o > 0; o >>= 1) v += __shfl_xor(v, o);
  return v;
}
__device__ __forceinline__ float wred_max(float v) {
#pragma unroll
  for (int o = 32; o > 0; o >>= 1) v = fmaxf(v, __shfl_xor(v, o));
  return v;
}
__device__ __forceinline__ float red16_max(float v) {
#pragma unroll
  for (int o = 8; o > 0; o >>= 1) v = fmaxf(v, __shfl_xor(v, o));
  return v;
}
__device__ __forceinline__ float red16_sum(float v) {
#pragma unroll
  for (int o = 8; o > 0; o >>= 1) v += __shfl_xor(v, o);
  return v;
}

// ---------------- concat: x = [templates broadcast | img_patch_feats] ----
__global__ __launch_bounds__(256) void concat_kernel(
    const float* __restrict__ tpl, const float* __restrict__ patches,
    float* __restrict__ x) {
  size_t i = (size_t)blockIdx.x * 256 + threadIdx.x;  // one float4 each
  const size_t total = (size_t)MROWS * (D_ / 4);
  if (i >= total) return;
  size_t row = i / (D_ / 4);
  int c = (int)(i % (D_ / 4)) * 4;
  size_t b = row / NTOK;
  int n = (int)(row % NTOK);
  float4 v;
  if (n < K_) v = *(const float4*)(tpl + (size_t)n * D_ + c);
  else        v = *(const float4*)(patches + ((size_t)b * P_ + (n - K_)) * D_ + c);
  *(float4*)(x + row * D_ + c) = v;
}

// ---------------- LayerNorm: 4 rows/block (4 waves), f16 hi/lo out --------
__global__ __launch_bounds__(256) void ln_split_kernel(
    const float* __restrict__ x, const float* __restrict__ w,
    const float* __restrict__ b, f16* __restrict__ yh, f16* __restrict__ yl,
    int nrows) {
  int row = blockIdx.x * 4 + (threadIdx.x >> 6);
  if (row >= nrows) return;
  int lane = threadIdx.x & 63;
  const float* xr = x + (size_t)row * D_;
  float4 v[3];
#pragma unroll
  for (int j = 0; j < 3; ++j) v[j] = *(const float4*)(xr + j * 256 + lane * 4);
  float s = 0.f, sq = 0.f;
#pragma unroll
  for (int j = 0; j < 3; ++j) {
    s += v[j].x + v[j].y + v[j].z + v[j].w;
    sq = fmaf(v[j].x, v[j].x, sq); sq = fmaf(v[j].y, v[j].y, sq);
    sq = fmaf(v[j].z, v[j].z, sq); sq = fmaf(v[j].w, v[j].w, sq);
  }
#pragma unroll
  for (int o = 32; o > 0; o >>= 1) { s += __shfl_xor(s, o); sq += __shfl_xor(sq, o); }
  float mean = s * (1.f / D_);
  float var = sq * (1.f / D_) - mean * mean;
  float rs = rsqrtf(var + 1e-5f);
#pragma unroll
  for (int j = 0; j < 3; ++j) {
    int col = j * 256 + lane * 4;
    float4 wv = *(const float4*)(w + col);
    float4 bv = *(const float4*)(b + col);
    float o0 = (v[j].x - mean) * rs * wv.x + bv.x;
    float o1 = (v[j].y - mean) * rs * wv.y + bv.y;
    float o2 = (v[j].z - mean) * rs * wv.z + bv.z;
    float o3 = (v[j].w - mean) * rs * wv.w + bv.w;
    f16x4 hi = {(f16)o0, (f16)o1, (f16)o2, (f16)o3};
    f16x4 lo = {(f16)(o0 - (float)hi[0]), (f16)(o1 - (float)hi[1]),
                (f16)(o2 - (float)hi[2]), (f16)(o3 - (float)hi[3])};
    *(f16x4*)&yh[(size_t)row * D_ + col] = hi;
    *(f16x4*)&yl[(size_t)row * D_ + col] = lo;
  }
}

// -------- weight transpose + f16 hi/lo split: W[K][N] -> Wt[N][K] --------
__global__ __launch_bounds__(256) void transpose_split(
    const float* __restrict__ W, f16* __restrict__ Wh, f16* __restrict__ Wl,
    int Kd, int Nd) {
  __shared__ float t[32][33];
  const int n0 = blockIdx.x * 32, k0 = blockIdx.y * 32;
  const int tx = threadIdx.x & 31, ty = threadIdx.x >> 5;  // 32 x 8
#pragma unroll
  for (int j = 0; j < 4; ++j)
    t[ty + 8 * j][tx] = W[(size_t)(k0 + ty + 8 * j) * Nd + n0 + tx];
  __syncthreads();
#pragma unroll
  for (int j = 0; j < 4; ++j) {
    float v = t[tx][ty + 8 * j];
    f16 hi = (f16)v;
    size_t off = (size_t)(n0 + ty + 8 * j) * Kd + k0 + tx;
    Wh[off] = hi;
    Wl[off] = (f16)(v - (float)hi);
  }
}

// -------- combine q_b (768) and kv_b (1536) into qkv_b (2304) -------------
__global__ __launch_bounds__(256) void combine_bias(
    const float* __restrict__ qb, const float* __restrict__ kvb,
    float* __restrict__ out) {
  int i = blockIdx.x * 256 + threadIdx.x;
  if (i < QKVN) out[i] = (i < D_) ? qb[i] : kvb[i - D_];
}

// ------- split-f16 MFMA GEMM: C = act(A @ Wt^T + bias) [+C] --------------
// 1D grid, XCD-chunked bijective remap (T1/m204) THEN band-ordered tile
// mapping: bands of 8 N-tiles, M-major inside a band -> the band's 8
// W-tiles (3.1 MB) stay L2-resident for the whole M sweep; A streams.
// 2-phase dbuf, counted vmcnt, chunk swizzle (unchanged).
template <int ACT, bool RESID, bool OUTSPLIT>
__global__ __launch_bounds__(256) void gemm_split(
    const f16* __restrict__ Ah, const f16* __restrict__ Al,
    const f16* __restrict__ Wh, const f16* __restrict__ Wl,
    const float* __restrict__ bias, float* __restrict__ Cf,
    f16* __restrict__ Ch, f16* __restrict__ Cl, int M, int N, int K) {
  __shared__ __align__(16) f16 S[2][4][128][32];
  const int tid = threadIdx.x;
  // --- XCD-aware bijective chunk remap (8 XCDs, round-robin dispatch) ---
  const int nwg = gridDim.x;
  const int bid = blockIdx.x;
  const int xcd = bid & 7, idx = bid >> 3;
  const int qc = nwg >> 3, rc = nwg & 7;
  const int o = (xcd < rc ? xcd * (qc + 1) : rc * (qc + 1) + (xcd - rc) * qc) + idx;
  // --- band-ordered tile mapping (bands of 8 N-tiles, m-major inside) ---
  const int ntx = N >> 7;
  const int mt = nwg / ntx;
  const int fullArea = (ntx >> 3) * (mt << 3);
  int band, r, bw;
  if (o < fullArea) { band = o / (mt << 3); r = o - band * (mt << 3); bw = 8; }
  else             { band = ntx >> 3;      r = o - fullArea;          bw = ntx & 7; }
  const int bn = (band * 8 + r % bw) * 128;
  const int bm = (r / bw) * 128;

  const int w = tid >> 6, lane = tid & 63;
  const int wm = (w & 1) * 64, wn = (w >> 1) * 64;
  const int fr = lane & 15, kg = lane >> 4;
  f32x4 acc[4][4];
  const f32x4 z = {0.f, 0.f, 0.f, 0.f};
#pragma unroll
  for (int i = 0; i < 4; ++i)
#pragma unroll
    for (int j = 0; j < 4; ++j) acc[i][j] = z;
  const int srow = tid >> 2;
  const int c_l  = (tid & 3) ^ ((tid >> 3) & 3);
  const int cswz = (kg ^ ((fr >> 1) & 3)) * 8;

  auto STAGE = [&](int k0, int buf) {
#pragma unroll
    for (int j = 0; j < 2; ++j) {
      int arow = bm + j * 64 + srow; if (arow >= M) arow = M - 1;
      int brow = bn + j * 64 + srow;
      size_t aoff = (size_t)arow * K + k0 + c_l * 8;
      size_t boff = (size_t)brow * K + k0 + c_l * 8;
      char* base = (char*)&S[buf][0][0][0] + j * 4096 + w * 1024;
      gload_lds16(Ah + aoff, base);
      gload_lds16(Al + aoff, base + 8192);
      gload_lds16(Wh + boff, base + 16384);
      gload_lds16(Wl + boff, base + 24576);
    }
  };
  auto COMPUTE = [&](int buf) {
    f16x8 ah[4], al[4], bh[4], bl[4];
#pragma unroll
    for (int i = 0; i < 4; ++i) {
      ah[i] = *(const f16x8*)&S[buf][0][wm + i * 16 + fr][cswz];
      al[i] = *(const f16x8*)&S[buf][1][wm + i * 16 + fr][cswz];
      bh[i] = *(const f16x8*)&S[buf][2][wn + i * 16 + fr][cswz];
      bl[i] = *(const f16x8*)&S[buf][3][wn + i * 16 + fr][cswz];
    }
#pragma unroll
    for (int i = 0; i < 4; ++i)
#pragma unroll
      for (int j = 0; j < 4; ++j) {
        acc[i][j] = __builtin_amdgcn_mfma_f32_16x16x32_f16(ah[i], bh[j], acc[i][j], 0, 0, 0);
        acc[i][j] = __builtin_amdgcn_mfma_f32_16x16x32_f16(ah[i], bl[j], acc[i][j], 0, 0, 0);
        acc[i][j] = __builtin_amdgcn_mfma_f32_16x16x32_f16(al[i], bh[j], acc[i][j], 0, 0, 0);
      }
  };

  const int nt = K / 32;
  int cur = 0;
  STAGE(0, 0);
  for (int t = 0; t < nt - 1; ++t) {
    STAGE((t + 1) * 32, cur ^ 1);
    asm volatile("s_waitcnt vmcnt(8)" ::: "memory");
    __builtin_amdgcn_s_barrier();
    __builtin_amdgcn_sched_barrier(0);
    COMPUTE(cur);
    __builtin_amdgcn_s_barrier();
    cur ^= 1;
  }
  asm volatile("s_waitcnt vmcnt(0)" ::: "memory");
  __builtin_amdgcn_s_barrier();
  __builtin_amdgcn_sched_barrier(0);
  COMPUTE(cur);

#pragma unroll
  for (int j = 0; j < 4; ++j) {
    const int gc = bn + wn + j * 16 + fr;
    const float bv = bias[gc];
#pragma unroll
    for (int i = 0; i < 4; ++i) {
#pragma unroll
      for (int rg = 0; rg < 4; ++rg) {
        int gr = bm + wm + i * 16 + kg * 4 + rg;
        if (gr < M) {
          float val = acc[i][j][rg] + bv;
          if (ACT == 1) val = fmaxf(val, 0.f);
          if (ACT == 2) val = 1.f / (1.f + expf(-val));
          size_t off = (size_t)gr * N + gc;
          if (OUTSPLIT) {
            f16 hi = (f16)val;
            Ch[off] = hi;
            Cl[off] = (f16)(val - (float)hi);
          } else {
            if (RESID) val += Cf[off];
            Cf[off] = val;
          }
        }
      }
    }
  }
}

// ---------------- MFMA flash attention, split-f16 3-pass ------------------
// Q/K/V read from fused qkv buffer [row][2304]: q +0, k +768, v +1536.
__global__ __launch_bounds__(256) void attn_mfma(
    const f16* __restrict__ QKVh, const f16* __restrict__ QKVl,
    f16* __restrict__ Oh, f16* __restrict__ Ol) {
  __shared__ __align__(16) f16 Ksh[64][64];
  __shared__ __align__(16) f16 Ksl[64][64];
  __shared__ __align__(16) f16 Vsh[64][64];
  __shared__ __align__(16) f16 Vsl[64][64];
  __shared__ __align__(16) f16 Psh[4][32][64];
  __shared__ __align__(16) f16 Psl[4][32][64];
  const int b = blockIdx.x, h = blockIdx.y, zb = blockIdx.z;
  const int tid = threadIdx.x, w = tid >> 6, lane = tid & 63;
  const int fr = lane & 15, kg = lane >> 4;
  const int qbase = zb * 128 + w * 32;
  const size_t rowbase = (size_t)b * NTOK;
  const int hoff = h * HD_;
  const f32x4 z4 = {0.f, 0.f, 0.f, 0.f};

  f16x8 qfh[2][2], qfl[2][2];
#pragma unroll
  for (int mf = 0; mf < 2; ++mf) {
    int qr = qbase + mf * 16 + fr; if (qr >= NTOK) qr = NTOK - 1;
    const size_t ro = (rowbase + qr) * QKVN + hoff;
#pragma unroll
    for (int ks = 0; ks < 2; ++ks) {
      qfh[mf][ks] = *(const f16x8*)&QKVh[ro + ks * 32 + kg * 8];
      qfl[mf][ks] = *(const f16x8*)&QKVl[ro + ks * 32 + kg * 8];
    }
  }

  f32x4 oacc[2][4];
#pragma unroll
  for (int mf = 0; mf < 2; ++mf)
#pragma unroll
    for (int df = 0; df < 4; ++df) oacc[mf][df] = z4;
  float m_r[2][4], l_r[2][4];
#pragma unroll
  for (int mf = 0; mf < 2; ++mf)
#pragma unroll
    for (int rg = 0; rg < 4; ++rg) { m_r[mf][rg] = -INFINITY; l_r[mf][rg] = 0.f; }

  for (int t = 0; t < 4; ++t) {
    const int t0 = t * 64;
    __syncthreads();
#pragma unroll
    for (int s = 0; s < 2; ++s) {
      int slot = tid + s * 256;
      int trow = slot >> 3, pch = slot & 7;
      int lch = pch ^ (trow & 7);
      int tok = t0 + trow; if (tok >= NTOK) tok = NTOK - 1;
      size_t src = (rowbase + tok) * (size_t)QKVN + D_ + hoff + lch * 8;
      gload_lds16(QKVh + src, (char*)&Ksh[0][0] + s * 4096 + w * 1024);
      gload_lds16(QKVl + src, (char*)&Ksl[0][0] + s * 4096 + w * 1024);
    }
    {
      int tloc = tid & 63, dg = tid >> 6;
      int tok = t0 + tloc; if (tok >= NTOK) tok = NTOK - 1;
      size_t src = (rowbase + tok) * (size_t)QKVN + 2 * D_ + hoff + dg * 16;
      f16x8 v0h = *(const f16x8*)&QKVh[src];
      f16x8 v1h = *(const f16x8*)&QKVh[src + 8];
      f16x8 v0l = *(const f16x8*)&QKVl[src];
      f16x8 v1l = *(const f16x8*)&QKVl[src + 8];
      int ch = tloc >> 3, pos = tloc & 7;
#pragma unroll
      for (int i = 0; i < 8; ++i) {
        int d0 = dg * 16 + i, d1 = d0 + 8;
        Vsh[d0][((ch ^ (d0 & 7)) << 3) | pos] = v0h[i];
        Vsh[d1][((ch ^ (d1 & 7)) << 3) | pos] = v1h[i];
        Vsl[d0][((ch ^ (d0 & 7)) << 3) | pos] = v0l[i];
        Vsl[d1][((ch ^ (d1 & 7)) << 3) | pos] = v1l[i];
      }
    }
    __syncthreads();
    f16x8 kbh[4][2], kbl[4][2];
#pragma unroll
    for (int nf = 0; nf < 4; ++nf)
#pragma unroll
      for (int ks = 0; ks < 2; ++ks) {
        int phys = (((ks * 4 + kg) ^ (fr & 7))) * 8;
        kbh[nf][ks] = *(const f16x8*)&Ksh[nf * 16 + fr][phys];
        kbl[nf][ks] = *(const f16x8*)&Ksl[nf * 16 + fr][phys];
      }
    f32x4 sacc[2][4];
#pragma unroll
    for (int mf = 0; mf < 2; ++mf)
#pragma unroll
      for (int nf = 0; nf < 4; ++nf) sacc[mf][nf] = z4;
#pragma unroll
    for (int ks = 0; ks < 2; ++ks)
#pragma unroll
      for (int mf = 0; mf < 2; ++mf)
#pragma unroll
        for (int nf = 0; nf < 4; ++nf) {
          sacc[mf][nf] = __builtin_amdgcn_mfma_f32_16x16x32_f16(qfh[mf][ks], kbh[nf][ks], sacc[mf][nf], 0, 0, 0);
          sacc[mf][nf] = __builtin_amdgcn_mfma_f32_16x16x32_f16(qfh[mf][ks], kbl[nf][ks], sacc[mf][nf], 0, 0, 0);
          sacc[mf][nf] = __builtin_amdgcn_mfma_f32_16x16x32_f16(qfl[mf][ks], kbh[nf][ks], sacc[mf][nf], 0, 0, 0);
        }
#pragma unroll
    for (int nf = 0; nf < 4; ++nf) {
      bool valid = (t0 + nf * 16 + fr) < NTOK;
#pragma unroll
      for (int mf = 0; mf < 2; ++mf)
#pragma unroll
        for (int rg = 0; rg < 4; ++rg)
          sacc[mf][nf][rg] = valid ? sacc[mf][nf][rg] * 0.125f : -INFINITY;
    }
#pragma unroll
    for (int mf = 0; mf < 2; ++mf) {
      float scl[4];
#pragma unroll
      for (int rg = 0; rg < 4; ++rg) {
        float mx = fmaxf(fmaxf(sacc[mf][0][rg], sacc[mf][1][rg]),
                         fmaxf(sacc[mf][2][rg], sacc[mf][3][rg]));
        mx = red16_max(mx);
        float nm = fmaxf(m_r[mf][rg], mx);
        scl[rg] = __expf(m_r[mf][rg] - nm);
        m_r[mf][rg] = nm;
        float ts = 0.f;
        int qlc = mf * 16 + kg * 4 + rg;
#pragma unroll
        for (int nf = 0; nf < 4; ++nf) {
          float p = __expf(sacc[mf][nf][rg] - nm);
          ts += p;
          f16 ph = (f16)p;
          int tl = nf * 16 + fr;
          int off = (((tl >> 3) ^ (qlc & 7)) << 3) | (tl & 7);
          Psh[w][qlc][off] = ph;
          Psl[w][qlc][off] = (f16)(p - (float)ph);
        }
        ts = red16_sum(ts);
        l_r[mf][rg] = l_r[mf][rg] * scl[rg] + ts;
      }
#pragma unroll
      for (int df = 0; df < 4; ++df)
#pragma unroll
        for (int rg = 0; rg < 4; ++rg)
          oacc[mf][df][rg] *= scl[rg];
    }
    f16x8 vbh[4][2], vbl[4][2];
#pragma unroll
    for (int df = 0; df < 4; ++df)
#pragma unroll
      for (int ks = 0; ks < 2; ++ks) {
        int phys = (((ks * 4 + kg) ^ (fr & 7))) * 8;
        vbh[df][ks] = *(const f16x8*)&Vsh[df * 16 + fr][phys];
        vbl[df][ks] = *(const f16x8*)&Vsl[df * 16 + fr][phys];
      }
    f16x8 pah[2][2], pal[2][2];
#pragma unroll
    for (int mf = 0; mf < 2; ++mf)
#pragma unroll
      for (int ks = 0; ks < 2; ++ks) {
        int phys = (((ks * 4 + kg) ^ (fr & 7))) * 8;
        pah[mf][ks] = *(const f16x8*)&Psh[w][mf * 16 + fr][phys];
        pal[mf][ks] = *(const f16x8*)&Psl[w][mf * 16 + fr][phys];
      }
#pragma unroll
    for (int ks = 0; ks < 2; ++ks)
#pragma unroll
      for (int mf = 0; mf < 2; ++mf)
#pragma unroll
        for (int df = 0; df < 4; ++df) {
          oacc[mf][df] = __builtin_amdgcn_mfma_f32_16x16x32_f16(pah[mf][ks], vbh[df][ks], oacc[mf][df], 0, 0, 0);
          oacc[mf][df] = __builtin_amdgcn_mfma_f32_16x16x32_f16(pah[mf][ks], vbl[df][ks], oacc[mf][df], 0, 0, 0);
          oacc[mf][df] = __builtin_amdgcn_mfma_f32_16x16x32_f16(pal[mf][ks], vbh[df][ks], oacc[mf][df], 0, 0, 0);
        }
  }
#pragma unroll
  for (int mf = 0; mf < 2; ++mf)
#pragma unroll
    for (int rg = 0; rg < 4; ++rg) {
      int qr = qbase + mf * 16 + kg * 4 + rg;
      if (qr < NTOK) {
        float inv = 1.f / l_r[mf][rg];
        size_t ro = (rowbase + qr) * D_ + hoff;
#pragma unroll
        for (int df = 0; df < 4; ++df) {
          float val = oacc[mf][df][rg] * inv;
          f16 hi = (f16)val;
          Oh[ro + df * 16 + fr] = hi;
          Ol[ro + df * 16 + fr] = (f16)(val - (float)hi);
        }
      }
    }
}

// ---------- gather x[:, :16, :] -> f16 hi/lo planes [2048][768] -----------
__global__ __launch_bounds__(256) void gather_split(
    const float* __restrict__ x, f16* __restrict__ oh, f16* __restrict__ ol) {
  int idx = blockIdx.x * 256 + threadIdx.x;
  if (idx >= B_ * K_ * (D_ / 4)) return;
  int row = idx / (D_ / 4);
  int c4 = (idx % (D_ / 4)) * 4;
  int b = row >> 4, k = row & 15;
  const float* src = x + ((size_t)(b * NTOK + k)) * D_ + c4;
  f16x4 hi, lo;
#pragma unroll
  for (int i = 0; i < 4; ++i) {
    float v = src[i];
    hi[i] = (f16)v;
    lo[i] = (f16)(v - (float)hi[i]);
  }
  *(f16x4*)&oh[(size_t)row * D_ + c4] = hi;
  *(f16x4*)&ol[(size_t)row * D_ + c4] = lo;
}

// ---------------- logits[b,k] = dot(lat[b,k,:], proj[b,:]) ----------------
__global__ __launch_bounds__(64) void logits_kernel(
    const float* __restrict__ lat, const float* __restrict__ proj,
    float* __restrict__ logits) {
  int bk = blockIdx.x;
  int b = bk >> 4;
  int lane = threadIdx.x;
  const float* lr = lat + (size_t)bk * TOK_;
  const float* pr = proj + (size_t)b * TOK_;
  float s = 0.f;
#pragma unroll
  for (int i = 0; i < 8; ++i) s = fmaf(lr[lane + 64 * i], pr[lane + 64 * i], s);
  s = wred_sum(s);
  if (lane == 0) logits[bk] = s;
}

// ---------------- softmax + topk select + normalize (1 wave per b) --------
__global__ __launch_bounds__(64) void select_kernel(
    const float* __restrict__ logits, const float* __restrict__ lat,
    float* __restrict__ out_sel, float* __restrict__ out_numr) {
  const int b = blockIdx.x;
  const int lane = threadIdx.x;
  __shared__ float aw_s[16];
  __shared__ int sel_id_s[8];
  __shared__ int numr_s;
  float v = (lane < 16) ? logits[b * 16 + lane] : -INFINITY;
  float mx = wred_max(v);
  float e = (lane < 16) ? expf(v - mx) : 0.f;
  float sum = wred_sum(e);
  float aw = e / sum;
  if (lane < 16) aw_s[lane] = aw;
  unsigned long long ball = __ballot(lane < 16 && aw > 0.05f);
  int counts = __popcll(ball);
  __syncthreads();
  if (lane == 0) {
    int num_r = counts < 1 ? 1 : (counts > TOPK_ ? TOPK_ : counts);
    numr_s = num_r;
    bool used[16];
#pragma unroll
    for (int i = 0; i < 16; ++i) used[i] = false;
    int sorted_idx[8];
    for (int j = 0; j < 8; ++j) {   // descending top-8 (ties: lowest index)
      float bv = -INFINITY; int bi = 0;
      for (int i = 0; i < 16; ++i)
        if (!used[i] && aw_s[i] > bv) { bv = aw_s[i]; bi = i; }
      used[bi] = true;
      sorted_idx[j] = bi;
    }
    int keys[8];
    for (int j = 0; j < 8; ++j) keys[j] = (j < num_r) ? sorted_idx[j] : (16 + j);
    bool kused[8];
    for (int j = 0; j < 8; ++j) kused[j] = false;
    for (int slot = 0; slot < 8; ++slot) {  // perm = argsort(keys), gather
      int bk = 1 << 30, bj = 0;
      for (int j = 0; j < 8; ++j)
        if (!kused[j] && keys[j] < bk) { bk = keys[j]; bj = j; }
      kused[bj] = true;
      sel_id_s[slot] = sorted_idx[bj];
    }
  }
  __syncthreads();
  for (int j = 0; j < 8; ++j) {
    int id = sel_id_s[j];
    const float* row = lat + ((size_t)b * 16 + id) * TOK_;
    float vals[8];
    float sq = 0.f;
#pragma unroll
    for (int i = 0; i < 8; ++i) {
      vals[i] = row[lane + 64 * i];
      sq = fmaf(vals[i], vals[i], sq);
    }
    sq = wred_sum(sq);
    float inv = 1.f / fmaxf(sqrtf(sq), 1e-12f);
#pragma unroll
    for (int i = 0; i < 8; ++i)
      out_sel[((size_t)b * 8 + j) * TOK_ + lane + 64 * i] = vals[i] * inv;
  }
  if (lane == 0) out_numr[b] = (float)numr_s;
}

// ---------------- host launcher -------------------------------------------
extern "C" void kernel_launch(void* const* d_in, const int* in_sizes, int n_in,
                              void* d_out, int out_size, void* d_ws, size_t ws_size,
                              hipStream_t stream) {
  const float* img_feature_proj = (const float*)d_in[0];
  const float* img_patch_feats  = (const float*)d_in[1];
  const float* templates        = (const float*)d_in[2];
  const float* ln1_w  = (const float*)d_in[3];
  const float* ln1_b  = (const float*)d_in[4];
  const float* q_w    = (const float*)d_in[5];
  const float* q_b    = (const float*)d_in[6];
  const float* kv_w   = (const float*)d_in[7];
  const float* kv_b   = (const float*)d_in[8];
  const float* proj_w = (const float*)d_in[9];
  const float* proj_b = (const float*)d_in[10];
  const float* ln2_w  = (const float*)d_in[11];
  const float* ln2_b  = (const float*)d_in[12];
  const float* fc1_w  = (const float*)d_in[13];
  const float* fc1_b  = (const float*)d_in[14];
  const float* fc2_w  = (const float*)d_in[15];
  const float* fc2_b  = (const float*)d_in[16];
  const float* att_fc_w = (const float*)d_in[17];
  const float* att_fc_b = (const float*)d_in[18];

  // ---- fixed workspace ----
  char* ws = (char*)d_ws;
  const size_t XB = (size_t)MROWS * D_ * 4;              // 83,755,008 B
  float* x_f = (float*)ws;  ws += XB;                    // residual fp32
  auto alloc_f16 = [&](size_t n) { f16* p = (f16*)ws; ws += n * 2; return p; };
  f16* wqkv_h = alloc_f16((size_t)QKVN * 768);
  f16* wqkv_l = alloc_f16((size_t)QKVN * 768);
  f16* wp_h   = alloc_f16((size_t)768 * 768);
  f16* wp_l   = alloc_f16((size_t)768 * 768);
  f16* wf1_h  = alloc_f16((size_t)1536 * 768);
  f16* wf1_l  = alloc_f16((size_t)1536 * 768);
  f16* wf2_h  = alloc_f16((size_t)768 * 1536);
  f16* wf2_l  = alloc_f16((size_t)768 * 1536);
  f16* awt_h  = alloc_f16((size_t)512 * 768);
  f16* awt_l  = alloc_f16((size_t)512 * 768);
  f16* lat_h  = alloc_f16((size_t)2048 * 768);
  f16* lat_l  = alloc_f16((size_t)2048 * 768);
  float* qkv_b  = (float*)ws; ws += QKVN * 4;
  float* lat    = (float*)ws; ws += (size_t)2048 * 512 * 4;
  float* logits = (float*)ws; ws += 8192;
  const size_t fixed_bytes = (size_t)(ws - (char*)d_ws);

  // ---- adaptive batch-chunk: h planes 4B + qkv planes 12B per elem-row ----
  int NB = B_;
  while (NB > 1) {
    size_t CHE = (size_t)NB * NTOK * D_;
    if (fixed_bytes + 16 * CHE <= ws_size) break;
    NB >>= 1;
  }
  const size_t CHE = (size_t)NB * NTOK * D_;
  f16* h_h   = (f16*)ws;                 // CHE
  f16* h_l   = h_h + CHE;                // CHE
  f16* qkvh  = h_l + CHE;                // 3*CHE
  f16* qkvl  = qkvh + 3 * CHE;           // 3*CHE
  f16* fc1o_h = qkvh;                    // alias: 2*CHE
  f16* fc1o_l = qkvl;                    // alias: 2*CHE

  // ---- concat ----
  {
    size_t total = (size_t)MROWS * (D_ / 4);
    concat_kernel<<<(unsigned)((total + 255) / 256), 256, 0, stream>>>(
        templates, img_patch_feats, x_f);
  }
  transpose_split<<<dim3(16, 24), 256, 0, stream>>>(att_fc_w, awt_h, awt_l, 768, 512);

  const int nchunks = B_ / NB;
  for (int l = 0; l < L_; ++l) {
    transpose_split<<<dim3(24, 24), 256, 0, stream>>>(q_w + (size_t)l * 768 * 768, wqkv_h, wqkv_l, 768, 768);
    transpose_split<<<dim3(48, 24), 256, 0, stream>>>(kv_w + (size_t)l * 768 * 1536,
        wqkv_h + (size_t)768 * 768, wqkv_l + (size_t)768 * 768, 768, 1536);
    combine_bias<<<(QKVN + 255) / 256, 256, 0, stream>>>(q_b + l * D_, kv_b + l * 1536, qkv_b);
    transpose_split<<<dim3(24, 24), 256, 0, stream>>>(proj_w + (size_t)l * 768 * 768, wp_h, wp_l, 768, 768);
    transpose_split<<<dim3(48, 24), 256, 0, stream>>>(fc1_w + (size_t)l * 768 * 1536, wf1_h, wf1_l, 768, 1536);
    transpose_split<<<dim3(24, 48), 256, 0, stream>>>(fc2_w + (size_t)l * 1536 * 768, wf2_h, wf2_l, 1536, 768);
    for (int c = 0; c < nchunks; ++c) {
      const int b0 = c * NB;
      const int Rc = NB * NTOK;
      const int mt = (Rc + 127) / 128;
      float* xc = x_f + (size_t)b0 * NTOK * D_;
      ln_split_kernel<<<(Rc + 3) / 4, 256, 0, stream>>>(xc, ln1_w + l * D_, ln1_b + l * D_, h_h, h_l, Rc);
      gemm_split<0, false, true><<<(QKVN / 128) * mt, 256, 0, stream>>>(
          h_h, h_l, wqkv_h, wqkv_l, qkv_b, nullptr, qkvh, qkvl, Rc, QKVN, 768);
      attn_mfma<<<dim3(NB, H_, 2), 256, 0, stream>>>(qkvh, qkvl, h_h, h_l);
      gemm_split<0, true, false><<<6 * mt, 256, 0, stream>>>(
          h_h, h_l, wp_h, wp_l, proj_b + l * D_, xc, nullptr, nullptr, Rc, 768, 768);
      ln_split_kernel<<<(Rc + 3) / 4, 256, 0, stream>>>(xc, ln2_w + l * D_, ln2_b + l * D_, h_h, h_l, Rc);
      gemm_split<1, false, true><<<12 * mt, 256, 0, stream>>>(
          h_h, h_l, wf1_h, wf1_l, fc1_b + l * 1536, nullptr, fc1o_h, fc1o_l, Rc, 1536, 768);
      gemm_split<0, true, false><<<6 * mt, 256, 0, stream>>>(
          fc1o_h, fc1o_l, wf2_h, wf2_l, fc2_b + l * D_, xc, nullptr, nullptr, Rc, 768, 1536);
    }
  }

  gather_split<<<(B_ * K_ * (D_ / 4) + 255) / 256, 256, 0, stream>>>(x_f, lat_h, lat_l);
  gemm_split<2, false, false><<<4 * 16, 256, 0, stream>>>(
      lat_h, lat_l, awt_h, awt_l, att_fc_b, lat, nullptr, nullptr, B_ * K_, TOK_, 768);

  logits_kernel<<<B_ * K_, 64, 0, stream>>>(lat, img_feature_proj, logits);
  select_kernel<<<B_, 64, 0, stream>>>(logits, lat, (float*)d_out,
                                       (float*)d_out + (size_t)B_ * TOPK_ * TOK_);
}